// Round 9
// baseline (2145.898 us; speedup 1.0000x reference)
//
#include <hip/hip_runtime.h>
#include <math.h>

// ---- problem constants (from reference) ----
#define N_   8192
#define E_   131072
#define T_   262144
#define H_   128
#define IND_ 64
#define G_   32
#define L_   2

// generic fp32 GEMM tiling (node_in only)
#define CW 64
#define RB 16

// MFMA fused MLP tiling
#define MROWS 32     // rows per wave (= per block now)
#define HSTRIDE 136  // LDS hidden row stride (bf16 elems)

// RBF constants
#define STEP_E  ((float)(5.0/31.0))
#define GAMMA_E ((float)(1.0/(2.0*((5.0/31.0)*(5.0/31.0) + 1e-12))))
#define PI_D    3.14159265358979323846
#define STEP_A  ((float)(PI_D/15.0))
#define GAMMA_A ((float)(1.0/(2.0*((PI_D/15.0)*(PI_D/15.0) + 1e-12))))

typedef __attribute__((ext_vector_type(8))) short short8;
typedef __attribute__((ext_vector_type(4))) float f32x4;
typedef unsigned short ushort_t;

static __device__ __forceinline__ float silu_f(float x){ return x / (1.f + expf(-x)); }
static __device__ __forceinline__ float sigmoid_f(float x){ return 1.f / (1.f + expf(-x)); }

static __device__ __forceinline__ ushort_t f2bf(float x){
  unsigned int u = __builtin_bit_cast(unsigned int, x);
  u += 0x7FFFu + ((u >> 16) & 1u);
  return (ushort_t)(u >> 16);
}
static __device__ __forceinline__ float bf2f(ushort_t h){
  unsigned int u = ((unsigned int)h) << 16;
  return __builtin_bit_cast(float, u);
}

// ---------------- small utility kernels ----------------

__global__ void k_zero(float* __restrict__ p, long n){
  long stride = (long)gridDim.x*256;
  long n4 = n >> 2;
  float4* p4 = (float4*)p;
  for (long i = (long)blockIdx.x*256 + threadIdx.x; i < n4; i += stride)
    p4[i] = make_float4(0.f,0.f,0.f,0.f);
  for (long i = (n4<<2) + (long)blockIdx.x*256 + threadIdx.x; i < n; i += stride)
    p[i] = 0.f;
}

__global__ void k_sentinel(float* __restrict__ p, int n){
  int i = blockIdx.x*256 + threadIdx.x;
  if (i < n) p[i] = 1.0e30f;
}

__global__ void k_init_vn(float* __restrict__ vn, const float* __restrict__ vn_init){
  int i = blockIdx.x*256 + threadIdx.x;
  if (i < G_*H_) vn[i] = vn_init[i & 127];
}

// weight convert+transpose (hi only): W fp32 [K][C] -> Wt bf16 [C][Kpad]
__global__ void k_wt(const float* __restrict__ W, ushort_t* __restrict__ Wt,
                     int K, int C, int Kpad){
  int i = blockIdx.x*256 + threadIdx.x;
  if (i >= C*Kpad) return;
  int c = i / Kpad, k = i % Kpad;
  Wt[i] = (k < K) ? f2bf(W[(size_t)k*C + c]) : (ushort_t)0;
}

// weight convert+transpose with residual: hi + lo (bf16x2 split)
__global__ void k_wt2(const float* __restrict__ W, ushort_t* __restrict__ Whi,
                      ushort_t* __restrict__ Wlo, int K, int C, int Kpad){
  int i = blockIdx.x*256 + threadIdx.x;
  if (i >= C*Kpad) return;
  int c = i / Kpad, k = i % Kpad;
  float w = (k < K) ? W[(size_t)k*C + c] : 0.f;
  ushort_t h = f2bf(w);
  Whi[i] = h;
  Wlo[i] = f2bf(w - bf2f(h));
}

// per-edge: vec, dir, edge RBF(32) in bf16
__global__ void k_geom(const float* __restrict__ pos, const float* __restrict__ dist,
                       const int* __restrict__ ei,
                       float* __restrict__ vec, float* __restrict__ dir,
                       ushort_t* __restrict__ rbf16){
  int e = blockIdx.x*256 + threadIdx.x;
  if (e >= E_) return;
  int s = ei[e], d = ei[E_ + e];
  float vx = pos[d*3+0] - pos[s*3+0];
  float vy = pos[d*3+1] - pos[s*3+1];
  float vz = pos[d*3+2] - pos[s*3+2];
  vec[e*3+0]=vx; vec[e*3+1]=vy; vec[e*3+2]=vz;
  float dd = dist[e];
  float inv = 1.f / (dd + 1e-9f);
  dir[e*3+0]=vx*inv; dir[e*3+1]=vy*inv; dir[e*3+2]=vz*inv;
  #pragma unroll
  for (int i=0;i<32;i++){
    float df = dd - i*STEP_E;
    rbf16[e*32+i] = f2bf(expf(-GAMMA_E*df*df));
  }
}

// per-triplet angle
__global__ void k_angle(const float* __restrict__ vec,
                        const int* __restrict__ kj, const int* __restrict__ ji,
                        float* __restrict__ angle){
  int t = blockIdx.x*256 + threadIdx.x;
  if (t >= T_) return;
  int ea = ji[t], eb = kj[t];
  float ax=vec[ea*3+0], ay=vec[ea*3+1], az=vec[ea*3+2];
  float bx=vec[eb*3+0], by=vec[eb*3+1], bz=vec[eb*3+2];
  float dot = ax*bx + ay*by + az*bz;
  float na = sqrtf(ax*ax+ay*ay+az*az + 1e-12f);
  float nb = sqrtf(bx*bx+by*by+bz*bz + 1e-12f);
  float c = dot / (na*nb + 1e-9f);
  c = fminf(fmaxf(c, -1.f + 1e-7f), 1.f - 1e-7f);
  angle[t] = acosf(c);
}

// ---------------- counting-sort kernels ----------------

__global__ void k_hist(const int* __restrict__ keys, int M, int* __restrict__ hist){
  int i = blockIdx.x*256 + threadIdx.x;
  if (i < M) atomicAdd(&hist[keys[i]], 1);
}

__global__ void k_hist2(const int* __restrict__ keys, const int* __restrict__ map,
                        int M, int* __restrict__ hist){
  int i = blockIdx.x*256 + threadIdx.x;
  if (i < M) atomicAdd(&hist[map[keys[i]]], 1);
}

__global__ void k_scan1(const int* __restrict__ in, int* __restrict__ out,
                        int* __restrict__ sums, int B){
  __shared__ int sh[1024];
  int base = blockIdx.x*1024, t = threadIdx.x;
  for (int j=t;j<1024;j+=256) sh[j] = (base+j<B) ? in[base+j] : 0;
  __syncthreads();
  for (int o=1;o<1024;o<<=1){
    int v[4];
    #pragma unroll
    for (int q=0;q<4;q++){ int idx=t+q*256; v[q]=(idx>=o)? sh[idx-o]:0; }
    __syncthreads();
    #pragma unroll
    for (int q=0;q<4;q++){ int idx=t+q*256; sh[idx]+=v[q]; }
    __syncthreads();
  }
  for (int j=t;j<1024;j+=256) if (base+j<B) out[base+j] = (j==0)?0:sh[j-1];
  if (t==0) sums[blockIdx.x] = sh[1023];
}

__global__ void k_scan2(int* __restrict__ sums, int nb){
  if (threadIdx.x==0 && blockIdx.x==0){
    int a=0;
    for (int i=0;i<nb;i++){ int x=sums[i]; sums[i]=a; a+=x; }
  }
}

__global__ void k_scan3(int* __restrict__ out, const int* __restrict__ sums, int B){
  int i = blockIdx.x*256+threadIdx.x;
  if (i<B) out[i] += sums[i>>10];
}

__global__ void k_fill(const int* __restrict__ keys, int M, int* __restrict__ cur,
                       int* __restrict__ perm){
  int i = blockIdx.x*256+threadIdx.x;
  if (i<M){ int p = atomicAdd(&cur[keys[i]],1); perm[p]=i; }
}

__global__ void k_fill2(const int* __restrict__ keys, const int* __restrict__ map,
                        int M, int* __restrict__ cur, int* __restrict__ perm){
  int i = blockIdx.x*256+threadIdx.x;
  if (i<M){ int p = atomicAdd(&cur[map[keys[i]]],1); perm[p]=i; }
}

__global__ void k_invert(const int* __restrict__ perm, int* __restrict__ rank, int M){
  int i = blockIdx.x*256+threadIdx.x;
  if (i<M) rank[perm[i]] = i;
}

// ---------------- MFMA fused 2-layer MLP + sorted segment-scatter ----------------
// ONE WAVE PER BLOCK (64 threads, 32 rows), zero barriers (hid/segk/dirs are
// wave-private LDS; DS unit is in-order per wave). Epilogue: each thread walks
// the 8 sorted rows it owns in its C-fragment (rows rh*16+quad*4+reg),
// pre-reduces same-segment runs, flushes one atomic per run.
// SM==1 (triplet): rows sorted by rank_e[ji]; scatter key = rank_e[ji]; eagg rows = rank.
// SM==2 (edge):    rows sorted by dst; eagg read positional (row = sorted position).
__launch_bounds__(64, 4)
__global__ void k_mlp2_mfma(int SM,
    const int* __restrict__ perm, const int* __restrict__ scatmap,
    const int* __restrict__ idx1, const int* __restrict__ idx2,
    const ushort_t* __restrict__ rbf16, const float* __restrict__ angle,
    const ushort_t* __restrict__ s16, const float* __restrict__ eagg_in,
    const ushort_t* __restrict__ W1t, const float* __restrict__ b1, int K1pad,
    const ushort_t* __restrict__ W2t, const float* __restrict__ b2, int OUTgrp,
    const float* __restrict__ dir,
    float* __restrict__ out0, float* __restrict__ out1)
{
  __shared__ ushort_t hid[MROWS*HSTRIDE];   // 8704 B
  __shared__ int   segk[MROWS];
  __shared__ float dirs[MROWS][3];
  const int lane = threadIdx.x;
  const int n    = lane & 15;
  const int quad = lane >> 4;
  const int kq   = quad*8;
  const int wrow = blockIdx.x*MROWS;

  // stage segment keys + dirs for this wave's 32 rows (lanes 0-31)
  if (lane < MROWS){
    int e = perm[wrow + lane];
    int key = idx2[e];
    segk[lane] = scatmap ? scatmap[key] : key;
    if (SM == 2){
      dirs[lane][0]=dir[e*3+0]; dirs[lane][1]=dir[e*3+1]; dirs[lane][2]=dir[e*3+2];
    }
  }

  const int e0 = perm[wrow + n];
  const int e1 = perm[wrow + 16 + n];

  int i1a = idx1[e0], i1b = idx1[e1];
  int i2a = idx2[e0], i2b = idx2[e1];
  float ang0 = 0.f, ang1 = 0.f;
  if (SM == 1){ ang0 = angle[e0]; ang1 = angle[e1]; }

  // ---------- phase A: hidden = silu(in @ W1 + b1) ----------
  f32x4 acc[2][8];
  #pragma unroll
  for (int rh=0;rh<2;rh++)
    #pragma unroll
    for (int ct=0;ct<8;ct++) acc[rh][ct] = (f32x4){0.f,0.f,0.f,0.f};

  for (int k0 = 0; k0 < K1pad; k0 += 32){
    short8 a0, a1;
    if (SM == 1){
      if (k0 == 0){
        a0 = *(const short8*)&rbf16[(size_t)i1a*32 + kq];
        a1 = *(const short8*)&rbf16[(size_t)i1b*32 + kq];
      } else if (k0 == 32){
        a0 = *(const short8*)&rbf16[(size_t)i2a*32 + kq];
        a1 = *(const short8*)&rbf16[(size_t)i2b*32 + kq];
      } else {
        #pragma unroll
        for (int j=0;j<8;j++){
          int kk = kq + j;
          float v0 = 0.f, v1 = 0.f;
          if (kk < 16){
            float c = (float)kk*STEP_A;
            float d0 = ang0 - c, d1 = ang1 - c;
            v0 = expf(-GAMMA_A*d0*d0); v1 = expf(-GAMMA_A*d1*d1);
          }
          a0[j] = (short)f2bf(v0); a1[j] = (short)f2bf(v1);
        }
      }
    } else {
      int k = k0 + kq;
      if (k0 < 128){
        a0 = *(const short8*)&s16[(size_t)i1a*128 + k];
        a1 = *(const short8*)&s16[(size_t)i1b*128 + k];
      } else if (k0 < 256){
        a0 = *(const short8*)&s16[(size_t)i2a*128 + (k-128)];
        a1 = *(const short8*)&s16[(size_t)i2b*128 + (k-128)];
      } else if (k0 < 288){
        a0 = *(const short8*)&rbf16[(size_t)e0*32 + (k-256)];
        a1 = *(const short8*)&rbf16[(size_t)e1*32 + (k-256)];
      } else {
        // eagg stored in sorted-edge-position order -> sequential rows
        const float* p0 = &eagg_in[(size_t)(wrow + n)*128 + (k-288)];
        const float* p1 = &eagg_in[(size_t)(wrow + 16 + n)*128 + (k-288)];
        f32x4 x0 = *(const f32x4*)p0, x1 = *(const f32x4*)(p0+4);
        f32x4 y0 = *(const f32x4*)p1, y1 = *(const f32x4*)(p1+4);
        #pragma unroll
        for (int j=0;j<4;j++){
          a0[j] = (short)f2bf(x0[j]); a0[4+j] = (short)f2bf(x1[j]);
          a1[j] = (short)f2bf(y0[j]); a1[4+j] = (short)f2bf(y1[j]);
        }
      }
    }
    #pragma unroll
    for (int ct=0;ct<8;ct++){
      short8 b = *(const short8*)&W1t[(size_t)(ct*16 + n)*K1pad + k0 + kq];
      acc[0][ct] = __builtin_amdgcn_mfma_f32_16x16x32_bf16(a0, b, acc[0][ct], 0,0,0);
      acc[1][ct] = __builtin_amdgcn_mfma_f32_16x16x32_bf16(a1, b, acc[1][ct], 0,0,0);
    }
  }

  // bias + silu -> LDS (wave-private, no barrier)
  #pragma unroll
  for (int rh=0;rh<2;rh++){
    #pragma unroll
    for (int ct=0;ct<8;ct++){
      int col = ct*16 + n;
      float bv = b1[col];
      #pragma unroll
      for (int reg=0;reg<4;reg++){
        int rloc = rh*16 + quad*4 + reg;
        float h = acc[rh][ct][reg] + bv;
        hid[rloc*HSTRIDE + col] = f2bf(silu_f(h));
      }
    }
  }

  // segment keys for the 8 rows this thread owns in the C-fragment
  int keys[8];
  #pragma unroll
  for (int rh=0;rh<2;rh++)
    #pragma unroll
    for (int reg=0;reg<4;reg++)
      keys[rh*4+reg] = segk[rh*16 + quad*4 + reg];

  // ---------- phase B: out = hidden @ W2 + b2, per-thread segment flush ----------
  for (int og=0; og<OUTgrp; og++){
    f32x4 acc2[2][8];
    #pragma unroll
    for (int rh=0;rh<2;rh++)
      #pragma unroll
      for (int ct=0;ct<8;ct++) acc2[rh][ct] = (f32x4){0.f,0.f,0.f,0.f};

    #pragma unroll
    for (int k0=0;k0<128;k0+=32){
      short8 a0 = *(const short8*)&hid[(size_t)(n)*HSTRIDE + k0 + kq];
      short8 a1 = *(const short8*)&hid[(size_t)(16 + n)*HSTRIDE + k0 + kq];
      #pragma unroll
      for (int ct=0;ct<8;ct++){
        short8 b = *(const short8*)&W2t[(size_t)(og*128 + ct*16 + n)*128 + k0 + kq];
        acc2[0][ct] = __builtin_amdgcn_mfma_f32_16x16x32_bf16(a0, b, acc2[0][ct], 0,0,0);
        acc2[1][ct] = __builtin_amdgcn_mfma_f32_16x16x32_bf16(a1, b, acc2[1][ct], 0,0,0);
      }
    }

    if (SM == 1 || og == 0){
      #pragma unroll
      for (int ct=0;ct<8;ct++){
        int col = ct*16 + n;
        float bv = b2[og*128 + col];
        float a = 0.f; int prev = keys[0];
        #pragma unroll
        for (int j=0;j<8;j++){
          int k = keys[j];
          if (k != prev){ atomicAdd(&out0[(size_t)prev*128 + col], a); a = 0.f; prev = k; }
          a += acc2[j>>2][ct][j&3] + bv;
        }
        atomicAdd(&out0[(size_t)prev*128 + col], a);
      }
    } else {
      float dxr[8], dyr[8], dzr[8];
      #pragma unroll
      for (int rh=0;rh<2;rh++)
        #pragma unroll
        for (int reg=0;reg<4;reg++){
          int r = rh*16 + quad*4 + reg;
          dxr[rh*4+reg]=dirs[r][0]; dyr[rh*4+reg]=dirs[r][1]; dzr[rh*4+reg]=dirs[r][2];
        }
      #pragma unroll
      for (int ct=0;ct<8;ct++){
        int col = ct*16 + n;
        float bv = b2[128 + col];
        float ax=0.f, ay=0.f, az=0.f; int prev = keys[0];
        #pragma unroll
        for (int j=0;j<8;j++){
          int k = keys[j];
          if (k != prev){
            size_t b = ((size_t)prev*128 + col)*3;
            atomicAdd(&out1[b+0], ax); atomicAdd(&out1[b+1], ay); atomicAdd(&out1[b+2], az);
            ax=ay=az=0.f; prev = k;
          }
          float m = acc2[j>>2][ct][j&3] + bv;
          ax += m*dxr[j]; ay += m*dyr[j]; az += m*dzr[j];
        }
        size_t b = ((size_t)prev*128 + col)*3;
        atomicAdd(&out1[b+0], ax); atomicAdd(&out1[b+1], ay); atomicAdd(&out1[b+2], az);
      }
    }
  }
}

// ---------------- prep: split aggs and ||v|| into bf16 hi/lo ----------------
__global__ void k_prep(const float* __restrict__ aggs, const float* __restrict__ v,
                       ushort_t* __restrict__ a16h, ushort_t* __restrict__ a16l,
                       ushort_t* __restrict__ vnh,  ushort_t* __restrict__ vnl){
  int i = blockIdx.x*256 + threadIdx.x;
  if (i >= N_*H_) return;
  float a = aggs[i];
  ushort_t ah = f2bf(a);
  a16h[i] = ah; a16l[i] = f2bf(a - bf2f(ah));
  float v0 = v[(size_t)i*3+0], v1 = v[(size_t)i*3+1], v2 = v[(size_t)i*3+2];
  float nv = sqrtf(v0*v0 + v1*v1 + v2*v2 + 1e-12f);
  ushort_t nh = f2bf(nv);
  vnh[i] = nh; vnl[i] = f2bf(nv - bf2f(nh));
}

// ---------------- MFMA node-update kernel (one wave per block, og = blockIdx.y) ----------------
__launch_bounds__(64, 4)
__global__ void k_node_mfma(
    const float* __restrict__ s_in,
    const ushort_t* __restrict__ a16h, const ushort_t* __restrict__ a16l,
    const ushort_t* __restrict__ vnh,  const ushort_t* __restrict__ vnl,
    float* __restrict__ s2, float* __restrict__ v_out,
    const float* __restrict__ aggv,
    const ushort_t* __restrict__ us1h, const ushort_t* __restrict__ us1l, const float* __restrict__ us_b1,
    const ushort_t* __restrict__ us2h, const ushort_t* __restrict__ us2l, const float* __restrict__ us_b2,
    const ushort_t* __restrict__ gv1h, const ushort_t* __restrict__ gv1l, const float* __restrict__ gv_b1,
    const ushort_t* __restrict__ gv2h, const ushort_t* __restrict__ gv2l, const float* __restrict__ gv_b2)
{
  __shared__ ushort_t hidh[32*HSTRIDE];   // 8704 B
  __shared__ ushort_t hidl[32*HSTRIDE];   // 8704 B
  const int lane = threadIdx.x;
  const int n    = lane & 15;
  const int quad = lane >> 4;
  const int kq   = quad*8;
  const int og   = blockIdx.y;
  const int wrow = blockIdx.x*32;
  const int r0 = wrow + n;
  const int r1 = wrow + 16 + n;

  const ushort_t* W1h = og ? gv1h : us1h;
  const ushort_t* W1l = og ? gv1l : us1l;
  const float*    B1  = og ? gv_b1 : us_b1;
  const ushort_t* W2h = og ? gv2h : us2h;
  const ushort_t* W2l = og ? gv2l : us2l;
  const float*    B2  = og ? gv_b2 : us_b2;

  // ---------- phase A: hidden = silu(ctx @ W1 + b1), bf16x3 ----------
  f32x4 acc[2][8];
  #pragma unroll
  for (int rh=0;rh<2;rh++)
    #pragma unroll
    for (int ct=0;ct<8;ct++) acc[rh][ct] = (f32x4){0.f,0.f,0.f,0.f};

  for (int k0=0; k0<384; k0+=32){
    short8 ah0, al0, ah1, al1;
    const int k = k0 + kq;
    if (k0 < 128){
      const float* p0 = &s_in[(size_t)r0*128 + k];
      const float* p1 = &s_in[(size_t)r1*128 + k];
      f32x4 x0 = *(const f32x4*)p0, x1 = *(const f32x4*)(p0+4);
      f32x4 y0 = *(const f32x4*)p1, y1 = *(const f32x4*)(p1+4);
      #pragma unroll
      for (int j=0;j<4;j++){
        ushort_t h;
        h = f2bf(x0[j]); ah0[j]   = (short)h; al0[j]   = (short)f2bf(x0[j] - bf2f(h));
        h = f2bf(x1[j]); ah0[4+j] = (short)h; al0[4+j] = (short)f2bf(x1[j] - bf2f(h));
        h = f2bf(y0[j]); ah1[j]   = (short)h; al1[j]   = (short)f2bf(y0[j] - bf2f(h));
        h = f2bf(y1[j]); ah1[4+j] = (short)h; al1[4+j] = (short)f2bf(y1[j] - bf2f(h));
      }
    } else if (k0 < 256){
      int kk = k - 128;
      ah0 = *(const short8*)&a16h[(size_t)r0*128 + kk];
      al0 = *(const short8*)&a16l[(size_t)r0*128 + kk];
      ah1 = *(const short8*)&a16h[(size_t)r1*128 + kk];
      al1 = *(const short8*)&a16l[(size_t)r1*128 + kk];
    } else {
      int kk = k - 256;
      ah0 = *(const short8*)&vnh[(size_t)r0*128 + kk];
      al0 = *(const short8*)&vnl[(size_t)r0*128 + kk];
      ah1 = *(const short8*)&vnh[(size_t)r1*128 + kk];
      al1 = *(const short8*)&vnl[(size_t)r1*128 + kk];
    }
    #pragma unroll
    for (int ct=0;ct<8;ct++){
      short8 bh = *(const short8*)&W1h[(size_t)(ct*16 + n)*384 + k0 + kq];
      short8 bl = *(const short8*)&W1l[(size_t)(ct*16 + n)*384 + k0 + kq];
      acc[0][ct] = __builtin_amdgcn_mfma_f32_16x16x32_bf16(ah0, bh, acc[0][ct], 0,0,0);
      acc[0][ct] = __builtin_amdgcn_mfma_f32_16x16x32_bf16(al0, bh, acc[0][ct], 0,0,0);
      acc[0][ct] = __builtin_amdgcn_mfma_f32_16x16x32_bf16(ah0, bl, acc[0][ct], 0,0,0);
      acc[1][ct] = __builtin_amdgcn_mfma_f32_16x16x32_bf16(ah1, bh, acc[1][ct], 0,0,0);
      acc[1][ct] = __builtin_amdgcn_mfma_f32_16x16x32_bf16(al1, bh, acc[1][ct], 0,0,0);
      acc[1][ct] = __builtin_amdgcn_mfma_f32_16x16x32_bf16(ah1, bl, acc[1][ct], 0,0,0);
    }
  }

  #pragma unroll
  for (int rh=0;rh<2;rh++){
    #pragma unroll
    for (int ct=0;ct<8;ct++){
      int col = ct*16 + n;
      float bv = B1[col];
      #pragma unroll
      for (int reg=0;reg<4;reg++){
        int rloc = rh*16 + quad*4 + reg;
        float h = silu_f(acc[rh][ct][reg] + bv);
        ushort_t hh = f2bf(h);
        hidh[rloc*HSTRIDE + col] = hh;
        hidl[rloc*HSTRIDE + col] = f2bf(h - bf2f(hh));
      }
    }
  }

  // ---------- phase B ----------
  f32x4 acc2[2][8];
  #pragma unroll
  for (int rh=0;rh<2;rh++)
    #pragma unroll
    for (int ct=0;ct<8;ct++) acc2[rh][ct] = (f32x4){0.f,0.f,0.f,0.f};

  #pragma unroll
  for (int k0=0;k0<128;k0+=32){
    short8 ah0 = *(const short8*)&hidh[(size_t)(n)*HSTRIDE + k0 + kq];
    short8 ah1 = *(const short8*)&hidh[(size_t)(16 + n)*HSTRIDE + k0 + kq];
    short8 al0 = *(const short8*)&hidl[(size_t)(n)*HSTRIDE + k0 + kq];
    short8 al1 = *(const short8*)&hidl[(size_t)(16 + n)*HSTRIDE + k0 + kq];
    #pragma unroll
    for (int ct=0;ct<8;ct++){
      short8 bh = *(const short8*)&W2h[(size_t)(ct*16 + n)*128 + k0 + kq];
      short8 bl = *(const short8*)&W2l[(size_t)(ct*16 + n)*128 + k0 + kq];
      acc2[0][ct] = __builtin_amdgcn_mfma_f32_16x16x32_bf16(ah0, bh, acc2[0][ct], 0,0,0);
      acc2[0][ct] = __builtin_amdgcn_mfma_f32_16x16x32_bf16(al0, bh, acc2[0][ct], 0,0,0);
      acc2[0][ct] = __builtin_amdgcn_mfma_f32_16x16x32_bf16(ah0, bl, acc2[0][ct], 0,0,0);
      acc2[1][ct] = __builtin_amdgcn_mfma_f32_16x16x32_bf16(ah1, bh, acc2[1][ct], 0,0,0);
      acc2[1][ct] = __builtin_amdgcn_mfma_f32_16x16x32_bf16(al1, bh, acc2[1][ct], 0,0,0);
      acc2[1][ct] = __builtin_amdgcn_mfma_f32_16x16x32_bf16(ah1, bl, acc2[1][ct], 0,0,0);
    }
  }

  if (og == 0){
    #pragma unroll
    for (int rh=0;rh<2;rh++){
      #pragma unroll
      for (int ct=0;ct<8;ct++){
        int col = ct*16 + n;
        float bv = B2[col];
        #pragma unroll
        for (int reg=0;reg<4;reg++){
          int row = wrow + rh*16 + quad*4 + reg;
          size_t idx = (size_t)row*128 + col;
          s2[idx] = s_in[idx] + acc2[rh][ct][reg] + bv;
        }
      }
    }
  } else {
    #pragma unroll
    for (int rh=0;rh<2;rh++){
      #pragma unroll
      for (int ct=0;ct<8;ct++){
        int col = ct*16 + n;
        float bv = B2[col];
        #pragma unroll
        for (int reg=0;reg<4;reg++){
          int row = wrow + rh*16 + quad*4 + reg;
          size_t idx = (size_t)row*128 + col;
          float g = sigmoid_f(acc2[rh][ct][reg] + bv);
          size_t base = idx*3;
          v_out[base+0] += g*aggv[base+0];
          v_out[base+1] += g*aggv[base+1];
          v_out[base+2] += g*aggv[base+2];
        }
      }
    }
  }
}

// ---------------- generic fp32 row-MLP GEMM (node_in only) ----------------
__launch_bounds__(128)
__global__ void k_gemm(const float* __restrict__ A,
                       const float* __restrict__ W,
                       const float* __restrict__ bias,
                       float* __restrict__ C, int R, int K)
{
  __shared__ float ws[CW*128];
  __shared__ float as[RB][CW];
  const int tid = threadIdx.x;
  const int nchunk = (K + CW - 1) / CW;

  for (int rb = blockIdx.x*RB; rb < R; rb += gridDim.x*RB){
    float acc[RB];
    #pragma unroll
    for (int r=0;r<RB;r++) acc[r] = 0.f;

    for (int c=0;c<nchunk;c++){
      const int k0 = c*CW;
      for (int i=tid; i<CW*128; i+=128){
        int kk = i >> 7, col = i & 127;
        int k = k0 + kk;
        ws[i] = (k < K) ? W[k*128 + col] : 0.f;
      }
      for (int i=tid; i<RB*CW; i+=128){
        int r  = i >> 6, kk = i & 63;
        int k  = k0 + kk;
        as[r][kk] = (k < K) ? A[(long)(rb+r)*K + k] : 0.f;
      }
      __syncthreads();
      #pragma unroll 4
      for (int kq2=0; kq2<CW/4; kq2++){
        float w0 = ws[(4*kq2+0)*128 + tid];
        float w1 = ws[(4*kq2+1)*128 + tid];
        float w2 = ws[(4*kq2+2)*128 + tid];
        float w3 = ws[(4*kq2+3)*128 + tid];
        #pragma unroll
        for (int r=0;r<RB;r++){
          const float4 av = *reinterpret_cast<const float4*>(&as[r][4*kq2]);
          acc[r] = fmaf(av.x, w0, acc[r]);
          acc[r] = fmaf(av.y, w1, acc[r]);
          acc[r] = fmaf(av.z, w2, acc[r]);
          acc[r] = fmaf(av.w, w3, acc[r]);
        }
      }
      __syncthreads();
    }

    const float bv = bias[tid];
    #pragma unroll
    for (int r=0;r<RB;r++)
      C[(long)(rb+r)*128 + tid] = acc[r] + bv;
  }
}

// ---------------- small fused kernels ----------------

__launch_bounds__(256)
__global__ void k_small_mlp2(const float* __restrict__ in,
                             const float* __restrict__ w1, const float* __restrict__ b1,
                             const float* __restrict__ w2, const float* __restrict__ b2,
                             float* __restrict__ outp, int accumulate){
  __shared__ float a[32][128];
  __shared__ float h[32][128];
  int tid = threadIdx.x;
  for (int i=tid;i<32*128;i+=256) a[i>>7][i&127] = in[i];
  __syncthreads();
  int col = tid & 127, rg = tid >> 7;
  float acc[16];
  #pragma unroll
  for (int r=0;r<16;r++) acc[r]=0.f;
  for (int k=0;k<128;k++){
    float w = w1[k*128+col];
    #pragma unroll
    for (int r=0;r<16;r++) acc[r] = fmaf(a[rg*16+r][k], w, acc[r]);
  }
  {
    float bv = b1[col];
    #pragma unroll
    for (int r=0;r<16;r++) h[rg*16+r][col] = silu_f(acc[r]+bv);
  }
  __syncthreads();
  #pragma unroll
  for (int r=0;r<16;r++) acc[r]=0.f;
  for (int k=0;k<128;k++){
    float w = w2[k*128+col];
    #pragma unroll
    for (int r=0;r<16;r++) acc[r] = fmaf(h[rg*16+r][k], w, acc[r]);
  }
  {
    float bv = b2[col];
    #pragma unroll
    for (int r=0;r<16;r++){
      int idx = (rg*16+r)*128+col;
      float val = acc[r]+bv;
      outp[idx] = accumulate ? outp[idx]+val : val;
    }
  }
}

__global__ void k_head(const float* __restrict__ gbuf,
                       const float* __restrict__ w1, const float* __restrict__ b1,
                       const float* __restrict__ w2, const float* __restrict__ b2,
                       float* __restrict__ outp){
  __shared__ float red[128];
  int g = blockIdx.x, tid = threadIdx.x;
  float acc = 0.f;
  for (int k=0;k<640;k++) acc = fmaf(gbuf[g*640+k], w1[k*128+tid], acc);
  float h = silu_f(acc + b1[tid]);
  red[tid] = h * w2[tid];
  __syncthreads();
  for (int o=64;o>0;o>>=1){ if (tid<o) red[tid]+=red[tid+o]; __syncthreads(); }
  if (tid == 0) outp[g] = red[0] + b2[0];
}

// ---------------- elementwise / reduction kernels ----------------

__global__ void k_sadd_batch(float* __restrict__ s, const float* __restrict__ t2,
                             const int* __restrict__ batch, ushort_t* __restrict__ s16){
  int i = blockIdx.x*256 + threadIdx.x;
  if (i >= N_*H_) return;
  int n = i >> 7, h = i & 127;
  float v = s[i] + t2[batch[n]*128 + h];
  s[i] = v;
  s16[i] = f2bf(v);
}

__global__ void k_ln_silu(const float* __restrict__ in, float* __restrict__ outp,
                          const float* __restrict__ g, const float* __restrict__ b){
  __shared__ float red[128];
  int n = blockIdx.x, tid = threadIdx.x;
  float x = in[n*128 + tid];
  red[tid] = x; __syncthreads();
  for (int o=64;o>0;o>>=1){ if (tid<o) red[tid]+=red[tid+o]; __syncthreads(); }
  float mu = red[0] * (1.f/128.f);
  __syncthreads();
  float dx = x - mu;
  red[tid] = dx*dx; __syncthreads();
  for (int o=64;o>0;o>>=1){ if (tid<o) red[tid]+=red[tid+o]; __syncthreads(); }
  float var = red[0] * (1.f/128.f);
  float y = dx * rsqrtf(var + 1e-5f) * g[tid] + b[tid];
  outp[n*128 + tid] = silu_f(y);
}

__global__ void k_segsum(const float* __restrict__ s, const int* __restrict__ batch,
                         float* __restrict__ ssum){
  int i = blockIdx.x*256 + threadIdx.x;
  if (i >= N_*H_) return;
  int n = i >> 7, h = i & 127;
  atomicAdd(&ssum[batch[n]*128 + h], s[i]);
}

__global__ void k_scatter_nf(const float* __restrict__ s, const float* __restrict__ v,
                             const int* __restrict__ batch, float* __restrict__ addp,
                             float* __restrict__ counts){
  int i = blockIdx.x*256 + threadIdx.x;
  if (i >= N_*256) return;
  int n = i >> 8, j = i & 255;
  float val;
  if (j < 128){
    val = s[n*128 + j];
  } else {
    int h = j - 128;
    float v0 = v[((size_t)n*128+h)*3+0], v1 = v[((size_t)n*128+h)*3+1], v2 = v[((size_t)n*128+h)*3+2];
    val = sqrtf(v0*v0 + v1*v1 + v2*v2 + 1e-12f);
  }
  int b = batch[n];
  atomicAdd(&addp[b*256 + j], val);
  if (j == 0) atomicAdd(&counts[b], 1.f);
}

__global__ void k_build_g(const float* __restrict__ addp, const float* __restrict__ counts,
                          const float* __restrict__ vn, float* __restrict__ gbuf){
  int i = blockIdx.x*256 + threadIdx.x;
  if (i >= G_*640) return;
  int g = i / 640, j = i % 640;
  float val;
  if (j < 256)       val = addp[g*256 + j];
  else if (j < 512)  val = addp[g*256 + (j-256)] / fmaxf(counts[g], 1.f);
  else               val = vn[g*128 + (j-512)];
  gbuf[i] = val;
}

// ---------------- host launcher ----------------

extern "C" void kernel_launch(void* const* d_in, const int* in_sizes, int n_in,
                              void* d_out, int out_size, void* d_ws, size_t ws_size,
                              hipStream_t stream)
{
  const float* x         = (const float*)d_in[0];
  const float* pos       = (const float*)d_in[1];
  const float* edist     = (const float*)d_in[2];
  const float* node_in_w = (const float*)d_in[3];
  const float* node_in_b = (const float*)d_in[4];
  const float* tm_w1 = (const float*)d_in[5];
  const float* tm_b1 = (const float*)d_in[6];
  const float* tm_w2 = (const float*)d_in[7];
  const float* tm_b2 = (const float*)d_in[8];
  const float* mm_w1 = (const float*)d_in[9];
  const float* mm_b1 = (const float*)d_in[10];
  const float* mm_w2 = (const float*)d_in[11];
  const float* mm_b2 = (const float*)d_in[12];
  const float* us_w1 = (const float*)d_in[13];
  const float* us_b1 = (const float*)d_in[14];
  const float* us_w2 = (const float*)d_in[15];
  const float* us_b2 = (const float*)d_in[16];
  const float* gv_w1 = (const float*)d_in[17];
  const float* gv_b1 = (const float*)d_in[18];
  const float* gv_w2 = (const float*)d_in[19];
  const float* gv_b2 = (const float*)d_in[20];
  const float* ln_g  = (const float*)d_in[21];
  const float* ln_b  = (const float*)d_in[22];
  const float* vn_init = (const float*)d_in[23];
  const float* v2n_w1 = (const float*)d_in[24];
  const float* v2n_b1 = (const float*)d_in[25];
  const float* v2n_w2 = (const float*)d_in[26];
  const float* v2n_b2 = (const float*)d_in[27];
  const float* n2v_w1 = (const float*)d_in[28];
  const float* n2v_b1 = (const float*)d_in[29];
  const float* n2v_w2 = (const float*)d_in[30];
  const float* n2v_b2 = (const float*)d_in[31];
  const float* head_w1 = (const float*)d_in[32];
  const float* head_b1 = (const float*)d_in[33];
  const float* head_w2 = (const float*)d_in[34];
  const float* head_b2 = (const float*)d_in[35];
  const int* ei    = (const int*)d_in[36];
  const int* t_kj  = (const int*)d_in[37];
  const int* t_ji  = (const int*)d_in[38];
  const int* batch = (const int*)d_in[39];
  float* out = (float*)d_out;

  // ---- workspace layout (~118.0 MiB) ----
  float* f = (float*)d_ws;
  size_t off = 0;
  auto alloc = [&](size_t n){ n = (n + 3) & ~(size_t)3; float* p = f + off; off += n; return p; };
  float*    vec    = alloc((size_t)E_*3);   // aliased: perm_t + perm_e after k_angle
  float*    dir    = alloc((size_t)E_*3);
  ushort_t* rbf16  = (ushort_t*)alloc((size_t)E_*16);
  float*    angle  = alloc((size_t)T_);
  float*    eagg   = alloc((size_t)E_*128);  // permuted-row layout; also hosts node scratch
  float*    s      = alloc((size_t)N_*128);
  ushort_t* s16    = (ushort_t*)alloc((size_t)N_*64);
  float*    v      = alloc((size_t)N_*384);
  float*    aggs   = alloc((size_t)N_*128);  // aliased: ihist in prologue
  float*    aggv   = alloc((size_t)N_*384);  // contiguous after aggs: zeroed together
  float*    rank_f = alloc((size_t)E_);      // rank_e (E ints)
  float*    wtbuf_f= alloc((size_t)376832);  // bf16 transposed weights (hi + node-lo)
  float*    vn     = alloc((size_t)G_*128);
  float*    tg2    = alloc((size_t)G_*128);
  float*    ssum   = alloc((size_t)G_*128);
  float*    addp   = alloc((size_t)G_*256);
  float*    counts = alloc((size_t)G_);
  float*    gbuf   = alloc((size_t)G_*640);

  if (off * sizeof(float) > ws_size){
    k_sentinel<<<1, 64, 0, stream>>>(out, G_);
    return;
  }

  // aliases
  int* perm_t = (int*)vec;
  int* perm_e = perm_t + T_;
  int* rank_e = (int*)rank_f;
  int* ihist  = (int*)aggs;           // prologue only
  int* isums  = ihist + 131072;
  // node-update scratch inside eagg (lifetime: after edge MLP, before next-layer eagg zero)
  ushort_t* a16h = (ushort_t*)eagg;                 // N*128 bf16
  ushort_t* a16l = a16h + (size_t)N_*128;
  ushort_t* vnh  = a16l + (size_t)N_*128;
  ushort_t* vnl  = vnh  + (size_t)N_*128;
  float*    s2   = (float*)(vnl + (size_t)N_*128);  // N*128 fp32

  ushort_t* wtp = (ushort_t*)wtbuf_f;
  ushort_t *wt_tm1[2], *wt_tm2[2], *wt_mm1[2], *wt_mm2[2];
  ushort_t *wt_us1h[2], *wt_us1l[2], *wt_us2h[2], *wt_us2l[2];
  ushort_t *wt_gv1h[2], *wt_gv1l[2], *wt_gv2h[2], *wt_gv2l[2];
  for (int l=0;l<2;l++){
    wt_tm1[l] = wtp; wtp += 128*96;
    wt_tm2[l] = wtp; wtp += 128*128;
    wt_mm1[l] = wtp; wtp += 128*416;
    wt_mm2[l] = wtp; wtp += 256*128;
    wt_us1h[l] = wtp; wtp += 128*384;
    wt_us1l[l] = wtp; wtp += 128*384;
    wt_us2h[l] = wtp; wtp += 128*128;
    wt_us2l[l] = wtp; wtp += 128*128;
    wt_gv1h[l] = wtp; wtp += 128*384;
    wt_gv1l[l] = wtp; wtp += 128*384;
    wt_gv2h[l] = wtp; wtp += 128*128;
    wt_gv2l[l] = wtp; wtp += 128*128;
  }

  auto zero = [&](float* p, long n){
    int blocks = (int)((n/4 + 255)/256); if (blocks > 16384) blocks = 16384; if (blocks < 1) blocks = 1;
    k_zero<<<blocks, 256, 0, stream>>>(p, n);
  };
  auto wt = [&](const float* W, ushort_t* Wt, int K, int C, int Kpad){
    int n = C*Kpad;
    k_wt<<<(n + 255)/256, 256, 0, stream>>>(W, Wt, K, C, Kpad);
  };
  auto wt2 = [&](const float* W, ushort_t* Whi, ushort_t* Wlo, int K, int C, int Kpad){
    int n = C*Kpad;
    k_wt2<<<(n + 255)/256, 256, 0, stream>>>(W, Whi, Wlo, K, C, Kpad);
  };
  auto csort = [&](const int* keys, const int* map, int M, int B, int* perm){
    zero((float*)ihist, B + (B+1023)/1024);
    if (map) k_hist2<<<(M+255)/256, 256, 0, stream>>>(keys, map, M, ihist);
    else     k_hist <<<(M+255)/256, 256, 0, stream>>>(keys, M, ihist);
    int nb = (B+1023)/1024;
    k_scan1<<<nb, 256, 0, stream>>>(ihist, ihist, isums, B);
    k_scan2<<<1, 64, 0, stream>>>(isums, nb);
    k_scan3<<<(B+255)/256, 256, 0, stream>>>(ihist, isums, B);
    if (map) k_fill2<<<(M+255)/256, 256, 0, stream>>>(keys, map, M, ihist, perm);
    else     k_fill <<<(M+255)/256, 256, 0, stream>>>(keys, M, ihist, perm);
  };

  // ---- prologue ----
  zero(v, (long)N_*384);
  k_init_vn<<<(G_*H_ + 255)/256, 256, 0, stream>>>(vn, vn_init);
  k_geom<<<(E_ + 255)/256, 256, 0, stream>>>(pos, edist, ei, vec, dir, rbf16);
  k_angle<<<(T_ + 255)/256, 256, 0, stream>>>(vec, t_kj, t_ji, angle);
  // edges sorted by dst, then rank_e = inverse perm, then triplets sorted by rank_e[ji]
  csort(ei+E_, nullptr, E_, N_, perm_e);
  k_invert<<<(E_+255)/256, 256, 0, stream>>>(perm_e, rank_e, E_);
  csort(t_ji, rank_e, T_, E_, perm_t);
  for (int l=0;l<2;l++){
    wt(tm_w1 + l*80*128,   wt_tm1[l],  80, 128,  96);
    wt(tm_w2 + l*128*128,  wt_tm2[l], 128, 128, 128);
    wt(mm_w1 + l*416*128,  wt_mm1[l], 416, 128, 416);
    wt(mm_w2 + l*128*256,  wt_mm2[l], 128, 256, 128);
    wt2(us_w1 + l*384*128, wt_us1h[l], wt_us1l[l], 384, 128, 384);
    wt2(us_w2 + l*128*128, wt_us2h[l], wt_us2l[l], 128, 128, 128);
    wt2(gv_w1 + l*384*128, wt_gv1h[l], wt_gv1l[l], 384, 128, 384);
    wt2(gv_w2 + l*128*128, wt_gv2h[l], wt_gv2l[l], 128, 128, 128);
  }
  k_gemm<<<512, 128, 0, stream>>>(x, node_in_w, node_in_b, s, N_, IND_);

  for (int l=0; l<L_; l++){
    // 1) s += v2n_mlp(vn)[batch]  (snapshots s16)
    k_small_mlp2<<<1, 256, 0, stream>>>(vn, v2n_w1, v2n_b1, v2n_w2, v2n_b2, tg2, 0);
    k_sadd_batch<<<(N_*H_ + 255)/256, 256, 0, stream>>>(s, tg2, batch, s16);

    // 2) triplet MLP (MFMA, 1-wave blocks, sorted by rank_e[ji]) -> eagg (permuted rows)
    zero(eagg, (long)E_*128);
    k_mlp2_mfma<<<T_/MROWS, 64, 0, stream>>>(1, perm_t, rank_e, t_kj, t_ji, rbf16, angle, s16, eagg,
        wt_tm1[l], tm_b1 + l*128, 96,
        wt_tm2[l], tm_b2 + l*128, 1, dir, eagg, nullptr);

    // 3) edge MLP (MFMA, 1-wave blocks, sorted by dst; eagg read sequentially) -> aggs, aggv
    zero(aggs, (long)N_*512);
    k_mlp2_mfma<<<E_/MROWS, 64, 0, stream>>>(2, perm_e, nullptr, ei, ei + E_, rbf16, angle, s16, eagg,
        wt_mm1[l], mm_b1 + l*128, 416,
        wt_mm2[l], mm_b2 + l*256, 2, dir, aggs, aggv);

    // 4) prep ctx hi/lo pieces (into eagg space — eagg is dead until next layer)
    k_prep<<<(N_*H_ + 255)/256, 256, 0, stream>>>(aggs, v, a16h, a16l, vnh, vnl);

    // 5+6) node update (s2 = s + us_mlp) + gated v update; one wave/block, og split
    k_node_mfma<<<dim3(N_/32, 2), 64, 0, stream>>>(s, a16h, a16l, vnh, vnl, s2, v, aggv,
        wt_us1h[l], wt_us1l[l], us_b1 + l*128, wt_us2h[l], wt_us2l[l], us_b2 + l*128,
        wt_gv1h[l], wt_gv1l[l], gv_b1 + l*128, wt_gv2h[l], wt_gv2l[l], gv_b2 + l*128);

    // 7) s = silu(LN(s2))
    k_ln_silu<<<N_, 128, 0, stream>>>(s2, s, ln_g + l*128, ln_b + l*128);

    // 8) vn += n2v_mlp(segment_sum(s, batch))
    zero(ssum, (long)G_*128);
    k_segsum<<<(N_*H_ + 255)/256, 256, 0, stream>>>(s, batch, ssum);
    k_small_mlp2<<<1, 256, 0, stream>>>(ssum, n2v_w1, n2v_b1, n2v_w2, n2v_b2, vn, 1);
  }

  // ---- readout ----
  zero(addp, (long)(G_*256 + G_));   // addp and counts contiguous
  k_scatter_nf<<<(N_*256 + 255)/256, 256, 0, stream>>>(s, v, batch, addp, counts);
  k_build_g<<<(G_*640 + 255)/256, 256, 0, stream>>>(addp, counts, vn, gbuf);
  k_head<<<G_, 128, 0, stream>>>(gbuf, head_w1, head_b1, head_w2, head_b2, out);
}

// Round 10
// 1295.602 us; speedup vs baseline: 1.6563x; 1.6563x over previous
//
#include <hip/hip_runtime.h>
#include <math.h>

// ---- problem constants (from reference) ----
#define N_   8192
#define E_   131072
#define T_   262144
#define H_   128
#define IND_ 64
#define G_   32
#define L_   2

// generic fp32 GEMM tiling (node_in only)
#define CW 64
#define RB 16

// MFMA fused MLP tiling
#define MROWS 32     // rows per wave
#define BROWS 128    // rows per block (4 waves)
#define HSTRIDE 136  // LDS hidden row stride (bf16 elems)

// RBF constants
#define STEP_E  ((float)(5.0/31.0))
#define GAMMA_E ((float)(1.0/(2.0*((5.0/31.0)*(5.0/31.0) + 1e-12))))
#define PI_D    3.14159265358979323846
#define STEP_A  ((float)(PI_D/15.0))
#define GAMMA_A ((float)(1.0/(2.0*((PI_D/15.0)*(PI_D/15.0) + 1e-12))))

typedef __attribute__((ext_vector_type(8))) short short8;
typedef __attribute__((ext_vector_type(4))) float f32x4;
typedef unsigned short ushort_t;

static __device__ __forceinline__ float silu_f(float x){ return x / (1.f + expf(-x)); }
static __device__ __forceinline__ float sigmoid_f(float x){ return 1.f / (1.f + expf(-x)); }

static __device__ __forceinline__ ushort_t f2bf(float x){
  unsigned int u = __builtin_bit_cast(unsigned int, x);
  u += 0x7FFFu + ((u >> 16) & 1u);
  return (ushort_t)(u >> 16);
}
static __device__ __forceinline__ float bf2f(ushort_t h){
  unsigned int u = ((unsigned int)h) << 16;
  return __builtin_bit_cast(float, u);
}

// ---------------- small utility kernels ----------------

__global__ void k_zero(float* __restrict__ p, long n){
  long stride = (long)gridDim.x*256;
  long n4 = n >> 2;
  float4* p4 = (float4*)p;
  for (long i = (long)blockIdx.x*256 + threadIdx.x; i < n4; i += stride)
    p4[i] = make_float4(0.f,0.f,0.f,0.f);
  for (long i = (n4<<2) + (long)blockIdx.x*256 + threadIdx.x; i < n; i += stride)
    p[i] = 0.f;
}

__global__ void k_sentinel(float* __restrict__ p, int n){
  int i = blockIdx.x*256 + threadIdx.x;
  if (i < n) p[i] = 1.0e30f;
}

__global__ void k_init_vn(float* __restrict__ vn, const float* __restrict__ vn_init){
  int i = blockIdx.x*256 + threadIdx.x;
  if (i < G_*H_) vn[i] = vn_init[i & 127];
}

// weight convert+transpose (hi only): W fp32 [K][C] -> Wt bf16 [C][Kpad]
__global__ void k_wt(const float* __restrict__ W, ushort_t* __restrict__ Wt,
                     int K, int C, int Kpad){
  int i = blockIdx.x*256 + threadIdx.x;
  if (i >= C*Kpad) return;
  int c = i / Kpad, k = i % Kpad;
  Wt[i] = (k < K) ? f2bf(W[(size_t)k*C + c]) : (ushort_t)0;
}

// weight convert+transpose with residual: hi + lo (bf16x2 split)
__global__ void k_wt2(const float* __restrict__ W, ushort_t* __restrict__ Whi,
                      ushort_t* __restrict__ Wlo, int K, int C, int Kpad){
  int i = blockIdx.x*256 + threadIdx.x;
  if (i >= C*Kpad) return;
  int c = i / Kpad, k = i % Kpad;
  float w = (k < K) ? W[(size_t)k*C + c] : 0.f;
  ushort_t h = f2bf(w);
  Whi[i] = h;
  Wlo[i] = f2bf(w - bf2f(h));
}

// per-edge: vec, dir, edge RBF(32) in bf16
__global__ void k_geom(const float* __restrict__ pos, const float* __restrict__ dist,
                       const int* __restrict__ ei,
                       float* __restrict__ vec, float* __restrict__ dir,
                       ushort_t* __restrict__ rbf16){
  int e = blockIdx.x*256 + threadIdx.x;
  if (e >= E_) return;
  int s = ei[e], d = ei[E_ + e];
  float vx = pos[d*3+0] - pos[s*3+0];
  float vy = pos[d*3+1] - pos[s*3+1];
  float vz = pos[d*3+2] - pos[s*3+2];
  vec[e*3+0]=vx; vec[e*3+1]=vy; vec[e*3+2]=vz;
  float dd = dist[e];
  float inv = 1.f / (dd + 1e-9f);
  dir[e*3+0]=vx*inv; dir[e*3+1]=vy*inv; dir[e*3+2]=vz*inv;
  #pragma unroll
  for (int i=0;i<32;i++){
    float df = dd - i*STEP_E;
    rbf16[e*32+i] = f2bf(expf(-GAMMA_E*df*df));
  }
}

// per-triplet angle
__global__ void k_angle(const float* __restrict__ vec,
                        const int* __restrict__ kj, const int* __restrict__ ji,
                        float* __restrict__ angle){
  int t = blockIdx.x*256 + threadIdx.x;
  if (t >= T_) return;
  int ea = ji[t], eb = kj[t];
  float ax=vec[ea*3+0], ay=vec[ea*3+1], az=vec[ea*3+2];
  float bx=vec[eb*3+0], by=vec[eb*3+1], bz=vec[eb*3+2];
  float dot = ax*bx + ay*by + az*bz;
  float na = sqrtf(ax*ax+ay*ay+az*az + 1e-12f);
  float nb = sqrtf(bx*bx+by*by+bz*bz + 1e-12f);
  float c = dot / (na*nb + 1e-9f);
  c = fminf(fmaxf(c, -1.f + 1e-7f), 1.f - 1e-7f);
  angle[t] = acosf(c);
}

// ---------------- counting-sort kernels ----------------

__global__ void k_hist(const int* __restrict__ keys, int M, int* __restrict__ hist){
  int i = blockIdx.x*256 + threadIdx.x;
  if (i < M) atomicAdd(&hist[keys[i]], 1);
}

__global__ void k_hist2(const int* __restrict__ keys, const int* __restrict__ map,
                        int M, int* __restrict__ hist){
  int i = blockIdx.x*256 + threadIdx.x;
  if (i < M) atomicAdd(&hist[map[keys[i]]], 1);
}

__global__ void k_scan1(const int* __restrict__ in, int* __restrict__ out,
                        int* __restrict__ sums, int B){
  __shared__ int sh[1024];
  int base = blockIdx.x*1024, t = threadIdx.x;
  for (int j=t;j<1024;j+=256) sh[j] = (base+j<B) ? in[base+j] : 0;
  __syncthreads();
  for (int o=1;o<1024;o<<=1){
    int v[4];
    #pragma unroll
    for (int q=0;q<4;q++){ int idx=t+q*256; v[q]=(idx>=o)? sh[idx-o]:0; }
    __syncthreads();
    #pragma unroll
    for (int q=0;q<4;q++){ int idx=t+q*256; sh[idx]+=v[q]; }
    __syncthreads();
  }
  for (int j=t;j<1024;j+=256) if (base+j<B) out[base+j] = (j==0)?0:sh[j-1];
  if (t==0) sums[blockIdx.x] = sh[1023];
}

__global__ void k_scan2(int* __restrict__ sums, int nb){
  if (threadIdx.x==0 && blockIdx.x==0){
    int a=0;
    for (int i=0;i<nb;i++){ int x=sums[i]; sums[i]=a; a+=x; }
  }
}

__global__ void k_scan3(int* __restrict__ out, const int* __restrict__ sums, int B){
  int i = blockIdx.x*256+threadIdx.x;
  if (i<B) out[i] += sums[i>>10];
}

__global__ void k_fill(const int* __restrict__ keys, int M, int* __restrict__ cur,
                       int* __restrict__ perm){
  int i = blockIdx.x*256+threadIdx.x;
  if (i<M){ int p = atomicAdd(&cur[keys[i]],1); perm[p]=i; }
}

__global__ void k_fill2(const int* __restrict__ keys, const int* __restrict__ map,
                        int M, int* __restrict__ cur, int* __restrict__ perm){
  int i = blockIdx.x*256+threadIdx.x;
  if (i<M){ int p = atomicAdd(&cur[map[keys[i]]],1); perm[p]=i; }
}

__global__ void k_invert(const int* __restrict__ perm, int* __restrict__ rank, int M){
  int i = blockIdx.x*256+threadIdx.x;
  if (i<M) rank[perm[i]] = i;
}

// ---------------- MFMA fused 2-layer MLP + sorted segment-scatter ----------------
// 128-row blocks (4 waves x 32 rows). ZERO barriers: all LDS (hid, mchunk, segk,
// dirs) is wave-private; DS ops are in-order within a wave. Epilogue: per og,
// per 16-col chunk (one ct), wave dumps its C-fragment to mchunk, lanes 0-31
// walk 16-row windows (same run-merge granularity as the round-8 best).
// SM==1 (triplet): rows sorted by rank_e[ji]; scatter key = rank_e[ji]; eagg rows = rank.
// SM==2 (edge):    rows sorted by dst; eagg read positional (row = sorted position).
__launch_bounds__(256, 3)
__global__ void k_mlp2_mfma(int SM,
    const int* __restrict__ perm, const int* __restrict__ scatmap,
    const int* __restrict__ idx1, const int* __restrict__ idx2,
    const ushort_t* __restrict__ rbf16, const float* __restrict__ angle,
    const ushort_t* __restrict__ s16, const float* __restrict__ eagg_in,
    const ushort_t* __restrict__ W1t, const float* __restrict__ b1, int K1pad,
    const ushort_t* __restrict__ W2t, const float* __restrict__ b2, int OUTgrp,
    const float* __restrict__ dir,
    float* __restrict__ out0, float* __restrict__ out1)
{
  __shared__ ushort_t hid[BROWS*HSTRIDE];   // 34816 B (wave-private 32-row slices)
  __shared__ float mchunk[4][MROWS][17];    // 8704 B  (wave-private)
  __shared__ int   segk[4][MROWS];          // 512 B
  __shared__ float dirs[4][MROWS][3];       // 1536 B
  const int tid  = threadIdx.x;
  const int wave = tid >> 6;
  const int lane = tid & 63;
  const int n    = lane & 15;
  const int quad = lane >> 4;
  const int kq   = quad*8;
  const int wrow = blockIdx.x*BROWS + wave*MROWS;
  const int lrow = wave*MROWS;

  // wave-private staging of segment keys + dirs (lanes 0-31)
  if (lane < MROWS){
    int e = perm[wrow + lane];
    int key = idx2[e];
    segk[wave][lane] = scatmap ? scatmap[key] : key;
    if (SM == 2){
      dirs[wave][lane][0]=dir[e*3+0]; dirs[wave][lane][1]=dir[e*3+1]; dirs[wave][lane][2]=dir[e*3+2];
    }
  }

  const int e0 = perm[wrow + n];
  const int e1 = perm[wrow + 16 + n];

  int i1a = idx1[e0], i1b = idx1[e1];
  int i2a = idx2[e0], i2b = idx2[e1];
  float ang0 = 0.f, ang1 = 0.f;
  if (SM == 1){ ang0 = angle[e0]; ang1 = angle[e1]; }

  // ---------- phase A: hidden = silu(in @ W1 + b1) ----------
  f32x4 acc[2][8];
  #pragma unroll
  for (int rh=0;rh<2;rh++)
    #pragma unroll
    for (int ct=0;ct<8;ct++) acc[rh][ct] = (f32x4){0.f,0.f,0.f,0.f};

  for (int k0 = 0; k0 < K1pad; k0 += 32){
    short8 a0, a1;
    if (SM == 1){
      if (k0 == 0){
        a0 = *(const short8*)&rbf16[(size_t)i1a*32 + kq];
        a1 = *(const short8*)&rbf16[(size_t)i1b*32 + kq];
      } else if (k0 == 32){
        a0 = *(const short8*)&rbf16[(size_t)i2a*32 + kq];
        a1 = *(const short8*)&rbf16[(size_t)i2b*32 + kq];
      } else {
        #pragma unroll
        for (int j=0;j<8;j++){
          int kk = kq + j;
          float v0 = 0.f, v1 = 0.f;
          if (kk < 16){
            float c = (float)kk*STEP_A;
            float d0 = ang0 - c, d1 = ang1 - c;
            v0 = expf(-GAMMA_A*d0*d0); v1 = expf(-GAMMA_A*d1*d1);
          }
          a0[j] = (short)f2bf(v0); a1[j] = (short)f2bf(v1);
        }
      }
    } else {
      int k = k0 + kq;
      if (k0 < 128){
        a0 = *(const short8*)&s16[(size_t)i1a*128 + k];
        a1 = *(const short8*)&s16[(size_t)i1b*128 + k];
      } else if (k0 < 256){
        a0 = *(const short8*)&s16[(size_t)i2a*128 + (k-128)];
        a1 = *(const short8*)&s16[(size_t)i2b*128 + (k-128)];
      } else if (k0 < 288){
        a0 = *(const short8*)&rbf16[(size_t)e0*32 + (k-256)];
        a1 = *(const short8*)&rbf16[(size_t)e1*32 + (k-256)];
      } else {
        // eagg stored in sorted-edge-position order -> sequential rows
        const float* p0 = &eagg_in[(size_t)(wrow + n)*128 + (k-288)];
        const float* p1 = &eagg_in[(size_t)(wrow + 16 + n)*128 + (k-288)];
        f32x4 x0 = *(const f32x4*)p0, x1 = *(const f32x4*)(p0+4);
        f32x4 y0 = *(const f32x4*)p1, y1 = *(const f32x4*)(p1+4);
        #pragma unroll
        for (int j=0;j<4;j++){
          a0[j] = (short)f2bf(x0[j]); a0[4+j] = (short)f2bf(x1[j]);
          a1[j] = (short)f2bf(y0[j]); a1[4+j] = (short)f2bf(y1[j]);
        }
      }
    }
    #pragma unroll
    for (int ct=0;ct<8;ct++){
      short8 b = *(const short8*)&W1t[(size_t)(ct*16 + n)*K1pad + k0 + kq];
      acc[0][ct] = __builtin_amdgcn_mfma_f32_16x16x32_bf16(a0, b, acc[0][ct], 0,0,0);
      acc[1][ct] = __builtin_amdgcn_mfma_f32_16x16x32_bf16(a1, b, acc[1][ct], 0,0,0);
    }
  }

  // bias + silu -> LDS (wave-private rows; no barrier)
  #pragma unroll
  for (int rh=0;rh<2;rh++){
    #pragma unroll
    for (int ct=0;ct<8;ct++){
      int col = ct*16 + n;
      float bv = b1[col];
      #pragma unroll
      for (int reg=0;reg<4;reg++){
        int rloc = lrow + rh*16 + quad*4 + reg;
        float h = acc[rh][ct][reg] + bv;
        hid[rloc*HSTRIDE + col] = f2bf(silu_f(h));
      }
    }
  }

  // ---------- phase B: out = hidden @ W2 + b2, wave-private segment flush ----------
  for (int og=0; og<OUTgrp; og++){
    f32x4 acc2[2][8];
    #pragma unroll
    for (int rh=0;rh<2;rh++)
      #pragma unroll
      for (int ct=0;ct<8;ct++) acc2[rh][ct] = (f32x4){0.f,0.f,0.f,0.f};

    #pragma unroll
    for (int k0=0;k0<128;k0+=32){
      short8 a0 = *(const short8*)&hid[(size_t)(lrow + n)*HSTRIDE + k0 + kq];
      short8 a1 = *(const short8*)&hid[(size_t)(lrow + 16 + n)*HSTRIDE + k0 + kq];
      #pragma unroll
      for (int ct=0;ct<8;ct++){
        short8 b = *(const short8*)&W2t[(size_t)(og*128 + ct*16 + n)*128 + k0 + kq];
        acc2[0][ct] = __builtin_amdgcn_mfma_f32_16x16x32_bf16(a0, b, acc2[0][ct], 0,0,0);
        acc2[1][ct] = __builtin_amdgcn_mfma_f32_16x16x32_bf16(a1, b, acc2[1][ct], 0,0,0);
      }
    }

    // 8 chunks of 16 cols (one ct per chunk); no barriers (wave-private LDS)
    for (int ct=0; ct<8; ct++){
      const int c0 = ct*16;
      {
        int col = c0 + n;
        float bv = b2[og*128 + col];
        #pragma unroll
        for (int rh=0;rh<2;rh++)
          #pragma unroll
          for (int reg=0;reg<4;reg++){
            int r = rh*16 + quad*4 + reg;
            mchunk[wave][r][n] = 0.f;  // placeholder overwritten below (keeps compiler honest about aliasing)
            mchunk[wave][r][n] = acc2[rh][ct][reg] + bv;
          }
      }
      if (lane < 32){
        const int col = c0 + (lane & 15);
        const int w0r = (lane >> 4) * 16;      // 2 windows x 16 rows
        if (SM == 1 || og == 0){
          float a = 0.f; int prev = segk[wave][w0r];
          for (int j=0;j<16;j++){
            int r = w0r + j;
            int k = segk[wave][r];
            if (k != prev){ atomicAdd(&out0[(size_t)prev*128 + col], a); a = 0.f; prev = k; }
            a += mchunk[wave][r][col - c0];
          }
          atomicAdd(&out0[(size_t)prev*128 + col], a);
        } else {
          float ax=0.f, ay=0.f, az=0.f; int prev = segk[wave][w0r];
          for (int j=0;j<16;j++){
            int r = w0r + j;
            int k = segk[wave][r];
            if (k != prev){
              size_t b = ((size_t)prev*128 + col)*3;
              atomicAdd(&out1[b+0], ax); atomicAdd(&out1[b+1], ay); atomicAdd(&out1[b+2], az);
              ax=ay=az=0.f; prev = k;
            }
            float m = mchunk[wave][r][col - c0];
            ax += m*dirs[wave][r][0]; ay += m*dirs[wave][r][1]; az += m*dirs[wave][r][2];
          }
          size_t b = ((size_t)prev*128 + col)*3;
          atomicAdd(&out1[b+0], ax); atomicAdd(&out1[b+1], ay); atomicAdd(&out1[b+2], az);
        }
      }
    }
  }
}

// ---------------- prep: split aggs and ||v|| into bf16 hi/lo ----------------
__global__ void k_prep(const float* __restrict__ aggs, const float* __restrict__ v,
                       ushort_t* __restrict__ a16h, ushort_t* __restrict__ a16l,
                       ushort_t* __restrict__ vnh,  ushort_t* __restrict__ vnl){
  int i = blockIdx.x*256 + threadIdx.x;
  if (i >= N_*H_) return;
  float a = aggs[i];
  ushort_t ah = f2bf(a);
  a16h[i] = ah; a16l[i] = f2bf(a - bf2f(ah));
  float v0 = v[(size_t)i*3+0], v1 = v[(size_t)i*3+1], v2 = v[(size_t)i*3+2];
  float nv = sqrtf(v0*v0 + v1*v1 + v2*v2 + 1e-12f);
  ushort_t nh = f2bf(nv);
  vnh[i] = nh; vnl[i] = f2bf(nv - bf2f(nh));
}

// ---------------- MFMA node-update kernel (one wave per block, og = blockIdx.y) ----------------
__launch_bounds__(64, 4)
__global__ void k_node_mfma(
    const float* __restrict__ s_in,
    const ushort_t* __restrict__ a16h, const ushort_t* __restrict__ a16l,
    const ushort_t* __restrict__ vnh,  const ushort_t* __restrict__ vnl,
    float* __restrict__ s2, float* __restrict__ v_out,
    const float* __restrict__ aggv,
    const ushort_t* __restrict__ us1h, const ushort_t* __restrict__ us1l, const float* __restrict__ us_b1,
    const ushort_t* __restrict__ us2h, const ushort_t* __restrict__ us2l, const float* __restrict__ us_b2,
    const ushort_t* __restrict__ gv1h, const ushort_t* __restrict__ gv1l, const float* __restrict__ gv_b1,
    const ushort_t* __restrict__ gv2h, const ushort_t* __restrict__ gv2l, const float* __restrict__ gv_b2)
{
  __shared__ ushort_t hidh[32*HSTRIDE];   // 8704 B
  __shared__ ushort_t hidl[32*HSTRIDE];   // 8704 B
  const int lane = threadIdx.x;
  const int n    = lane & 15;
  const int quad = lane >> 4;
  const int kq   = quad*8;
  const int og   = blockIdx.y;
  const int wrow = blockIdx.x*32;
  const int r0 = wrow + n;
  const int r1 = wrow + 16 + n;

  const ushort_t* W1h = og ? gv1h : us1h;
  const ushort_t* W1l = og ? gv1l : us1l;
  const float*    B1  = og ? gv_b1 : us_b1;
  const ushort_t* W2h = og ? gv2h : us2h;
  const ushort_t* W2l = og ? gv2l : us2l;
  const float*    B2  = og ? gv_b2 : us_b2;

  // ---------- phase A: hidden = silu(ctx @ W1 + b1), bf16x3 ----------
  f32x4 acc[2][8];
  #pragma unroll
  for (int rh=0;rh<2;rh++)
    #pragma unroll
    for (int ct=0;ct<8;ct++) acc[rh][ct] = (f32x4){0.f,0.f,0.f,0.f};

  for (int k0=0; k0<384; k0+=32){
    short8 ah0, al0, ah1, al1;
    const int k = k0 + kq;
    if (k0 < 128){
      const float* p0 = &s_in[(size_t)r0*128 + k];
      const float* p1 = &s_in[(size_t)r1*128 + k];
      f32x4 x0 = *(const f32x4*)p0, x1 = *(const f32x4*)(p0+4);
      f32x4 y0 = *(const f32x4*)p1, y1 = *(const f32x4*)(p1+4);
      #pragma unroll
      for (int j=0;j<4;j++){
        ushort_t h;
        h = f2bf(x0[j]); ah0[j]   = (short)h; al0[j]   = (short)f2bf(x0[j] - bf2f(h));
        h = f2bf(x1[j]); ah0[4+j] = (short)h; al0[4+j] = (short)f2bf(x1[j] - bf2f(h));
        h = f2bf(y0[j]); ah1[j]   = (short)h; al1[j]   = (short)f2bf(y0[j] - bf2f(h));
        h = f2bf(y1[j]); ah1[4+j] = (short)h; al1[4+j] = (short)f2bf(y1[j] - bf2f(h));
      }
    } else if (k0 < 256){
      int kk = k - 128;
      ah0 = *(const short8*)&a16h[(size_t)r0*128 + kk];
      al0 = *(const short8*)&a16l[(size_t)r0*128 + kk];
      ah1 = *(const short8*)&a16h[(size_t)r1*128 + kk];
      al1 = *(const short8*)&a16l[(size_t)r1*128 + kk];
    } else {
      int kk = k - 256;
      ah0 = *(const short8*)&vnh[(size_t)r0*128 + kk];
      al0 = *(const short8*)&vnl[(size_t)r0*128 + kk];
      ah1 = *(const short8*)&vnh[(size_t)r1*128 + kk];
      al1 = *(const short8*)&vnl[(size_t)r1*128 + kk];
    }
    #pragma unroll
    for (int ct=0;ct<8;ct++){
      short8 bh = *(const short8*)&W1h[(size_t)(ct*16 + n)*384 + k0 + kq];
      short8 bl = *(const short8*)&W1l[(size_t)(ct*16 + n)*384 + k0 + kq];
      acc[0][ct] = __builtin_amdgcn_mfma_f32_16x16x32_bf16(ah0, bh, acc[0][ct], 0,0,0);
      acc[0][ct] = __builtin_amdgcn_mfma_f32_16x16x32_bf16(al0, bh, acc[0][ct], 0,0,0);
      acc[0][ct] = __builtin_amdgcn_mfma_f32_16x16x32_bf16(ah0, bl, acc[0][ct], 0,0,0);
      acc[1][ct] = __builtin_amdgcn_mfma_f32_16x16x32_bf16(ah1, bh, acc[1][ct], 0,0,0);
      acc[1][ct] = __builtin_amdgcn_mfma_f32_16x16x32_bf16(al1, bh, acc[1][ct], 0,0,0);
      acc[1][ct] = __builtin_amdgcn_mfma_f32_16x16x32_bf16(ah1, bl, acc[1][ct], 0,0,0);
    }
  }

  #pragma unroll
  for (int rh=0;rh<2;rh++){
    #pragma unroll
    for (int ct=0;ct<8;ct++){
      int col = ct*16 + n;
      float bv = B1[col];
      #pragma unroll
      for (int reg=0;reg<4;reg++){
        int rloc = rh*16 + quad*4 + reg;
        float h = silu_f(acc[rh][ct][reg] + bv);
        ushort_t hh = f2bf(h);
        hidh[rloc*HSTRIDE + col] = hh;
        hidl[rloc*HSTRIDE + col] = f2bf(h - bf2f(hh));
      }
    }
  }

  // ---------- phase B ----------
  f32x4 acc2[2][8];
  #pragma unroll
  for (int rh=0;rh<2;rh++)
    #pragma unroll
    for (int ct=0;ct<8;ct++) acc2[rh][ct] = (f32x4){0.f,0.f,0.f,0.f};

  #pragma unroll
  for (int k0=0;k0<128;k0+=32){
    short8 ah0 = *(const short8*)&hidh[(size_t)(n)*HSTRIDE + k0 + kq];
    short8 ah1 = *(const short8*)&hidh[(size_t)(16 + n)*HSTRIDE + k0 + kq];
    short8 al0 = *(const short8*)&hidl[(size_t)(n)*HSTRIDE + k0 + kq];
    short8 al1 = *(const short8*)&hidl[(size_t)(16 + n)*HSTRIDE + k0 + kq];
    #pragma unroll
    for (int ct=0;ct<8;ct++){
      short8 bh = *(const short8*)&W2h[(size_t)(ct*16 + n)*128 + k0 + kq];
      short8 bl = *(const short8*)&W2l[(size_t)(ct*16 + n)*128 + k0 + kq];
      acc2[0][ct] = __builtin_amdgcn_mfma_f32_16x16x32_bf16(ah0, bh, acc2[0][ct], 0,0,0);
      acc2[0][ct] = __builtin_amdgcn_mfma_f32_16x16x32_bf16(al0, bh, acc2[0][ct], 0,0,0);
      acc2[0][ct] = __builtin_amdgcn_mfma_f32_16x16x32_bf16(ah0, bl, acc2[0][ct], 0,0,0);
      acc2[1][ct] = __builtin_amdgcn_mfma_f32_16x16x32_bf16(ah1, bh, acc2[1][ct], 0,0,0);
      acc2[1][ct] = __builtin_amdgcn_mfma_f32_16x16x32_bf16(al1, bh, acc2[1][ct], 0,0,0);
      acc2[1][ct] = __builtin_amdgcn_mfma_f32_16x16x32_bf16(ah1, bl, acc2[1][ct], 0,0,0);
    }
  }

  if (og == 0){
    #pragma unroll
    for (int rh=0;rh<2;rh++){
      #pragma unroll
      for (int ct=0;ct<8;ct++){
        int col = ct*16 + n;
        float bv = B2[col];
        #pragma unroll
        for (int reg=0;reg<4;reg++){
          int row = wrow + rh*16 + quad*4 + reg;
          size_t idx = (size_t)row*128 + col;
          s2[idx] = s_in[idx] + acc2[rh][ct][reg] + bv;
        }
      }
    }
  } else {
    #pragma unroll
    for (int rh=0;rh<2;rh++){
      #pragma unroll
      for (int ct=0;ct<8;ct++){
        int col = ct*16 + n;
        float bv = B2[col];
        #pragma unroll
        for (int reg=0;reg<4;reg++){
          int row = wrow + rh*16 + quad*4 + reg;
          size_t idx = (size_t)row*128 + col;
          float g = sigmoid_f(acc2[rh][ct][reg] + bv);
          size_t base = idx*3;
          v_out[base+0] += g*aggv[base+0];
          v_out[base+1] += g*aggv[base+1];
          v_out[base+2] += g*aggv[base+2];
        }
      }
    }
  }
}

// ---------------- generic fp32 row-MLP GEMM (node_in only) ----------------
__launch_bounds__(128)
__global__ void k_gemm(const float* __restrict__ A,
                       const float* __restrict__ W,
                       const float* __restrict__ bias,
                       float* __restrict__ C, int R, int K)
{
  __shared__ float ws[CW*128];
  __shared__ float as[RB][CW];
  const int tid = threadIdx.x;
  const int nchunk = (K + CW - 1) / CW;

  for (int rb = blockIdx.x*RB; rb < R; rb += gridDim.x*RB){
    float acc[RB];
    #pragma unroll
    for (int r=0;r<RB;r++) acc[r] = 0.f;

    for (int c=0;c<nchunk;c++){
      const int k0 = c*CW;
      for (int i=tid; i<CW*128; i+=128){
        int kk = i >> 7, col = i & 127;
        int k = k0 + kk;
        ws[i] = (k < K) ? W[k*128 + col] : 0.f;
      }
      for (int i=tid; i<RB*CW; i+=128){
        int r  = i >> 6, kk = i & 63;
        int k  = k0 + kk;
        as[r][kk] = (k < K) ? A[(long)(rb+r)*K + k] : 0.f;
      }
      __syncthreads();
      #pragma unroll 4
      for (int kq2=0; kq2<CW/4; kq2++){
        float w0 = ws[(4*kq2+0)*128 + tid];
        float w1 = ws[(4*kq2+1)*128 + tid];
        float w2 = ws[(4*kq2+2)*128 + tid];
        float w3 = ws[(4*kq2+3)*128 + tid];
        #pragma unroll
        for (int r=0;r<RB;r++){
          const float4 av = *reinterpret_cast<const float4*>(&as[r][4*kq2]);
          acc[r] = fmaf(av.x, w0, acc[r]);
          acc[r] = fmaf(av.y, w1, acc[r]);
          acc[r] = fmaf(av.z, w2, acc[r]);
          acc[r] = fmaf(av.w, w3, acc[r]);
        }
      }
      __syncthreads();
    }

    const float bv = bias[tid];
    #pragma unroll
    for (int r=0;r<RB;r++)
      C[(long)(rb+r)*128 + tid] = acc[r] + bv;
  }
}

// ---------------- small fused kernels ----------------

__launch_bounds__(256)
__global__ void k_small_mlp2(const float* __restrict__ in,
                             const float* __restrict__ w1, const float* __restrict__ b1,
                             const float* __restrict__ w2, const float* __restrict__ b2,
                             float* __restrict__ outp, int accumulate){
  __shared__ float a[32][128];
  __shared__ float h[32][128];
  int tid = threadIdx.x;
  for (int i=tid;i<32*128;i+=256) a[i>>7][i&127] = in[i];
  __syncthreads();
  int col = tid & 127, rg = tid >> 7;
  float acc[16];
  #pragma unroll
  for (int r=0;r<16;r++) acc[r]=0.f;
  for (int k=0;k<128;k++){
    float w = w1[k*128+col];
    #pragma unroll
    for (int r=0;r<16;r++) acc[r] = fmaf(a[rg*16+r][k], w, acc[r]);
  }
  {
    float bv = b1[col];
    #pragma unroll
    for (int r=0;r<16;r++) h[rg*16+r][col] = silu_f(acc[r]+bv);
  }
  __syncthreads();
  #pragma unroll
  for (int r=0;r<16;r++) acc[r]=0.f;
  for (int k=0;k<128;k++){
    float w = w2[k*128+col];
    #pragma unroll
    for (int r=0;r<16;r++) acc[r] = fmaf(h[rg*16+r][k], w, acc[r]);
  }
  {
    float bv = b2[col];
    #pragma unroll
    for (int r=0;r<16;r++){
      int idx = (rg*16+r)*128+col;
      float val = acc[r]+bv;
      outp[idx] = accumulate ? outp[idx]+val : val;
    }
  }
}

__global__ void k_head(const float* __restrict__ gbuf,
                       const float* __restrict__ w1, const float* __restrict__ b1,
                       const float* __restrict__ w2, const float* __restrict__ b2,
                       float* __restrict__ outp){
  __shared__ float red[128];
  int g = blockIdx.x, tid = threadIdx.x;
  float acc = 0.f;
  for (int k=0;k<640;k++) acc = fmaf(gbuf[g*640+k], w1[k*128+tid], acc);
  float h = silu_f(acc + b1[tid]);
  red[tid] = h * w2[tid];
  __syncthreads();
  for (int o=64;o>0;o>>=1){ if (tid<o) red[tid]+=red[tid+o]; __syncthreads(); }
  if (tid == 0) outp[g] = red[0] + b2[0];
}

// ---------------- elementwise / reduction kernels ----------------

__global__ void k_sadd_batch(float* __restrict__ s, const float* __restrict__ t2,
                             const int* __restrict__ batch, ushort_t* __restrict__ s16){
  int i = blockIdx.x*256 + threadIdx.x;
  if (i >= N_*H_) return;
  int n = i >> 7, h = i & 127;
  float v = s[i] + t2[batch[n]*128 + h];
  s[i] = v;
  s16[i] = f2bf(v);
}

__global__ void k_ln_silu(const float* __restrict__ in, float* __restrict__ outp,
                          const float* __restrict__ g, const float* __restrict__ b){
  __shared__ float red[128];
  int n = blockIdx.x, tid = threadIdx.x;
  float x = in[n*128 + tid];
  red[tid] = x; __syncthreads();
  for (int o=64;o>0;o>>=1){ if (tid<o) red[tid]+=red[tid+o]; __syncthreads(); }
  float mu = red[0] * (1.f/128.f);
  __syncthreads();
  float dx = x - mu;
  red[tid] = dx*dx; __syncthreads();
  for (int o=64;o>0;o>>=1){ if (tid<o) red[tid]+=red[tid+o]; __syncthreads(); }
  float var = red[0] * (1.f/128.f);
  float y = dx * rsqrtf(var + 1e-5f) * g[tid] + b[tid];
  outp[n*128 + tid] = silu_f(y);
}

__global__ void k_segsum(const float* __restrict__ s, const int* __restrict__ batch,
                         float* __restrict__ ssum){
  int i = blockIdx.x*256 + threadIdx.x;
  if (i >= N_*H_) return;
  int n = i >> 7, h = i & 127;
  atomicAdd(&ssum[batch[n]*128 + h], s[i]);
}

__global__ void k_scatter_nf(const float* __restrict__ s, const float* __restrict__ v,
                             const int* __restrict__ batch, float* __restrict__ addp,
                             float* __restrict__ counts){
  int i = blockIdx.x*256 + threadIdx.x;
  if (i >= N_*256) return;
  int n = i >> 8, j = i & 255;
  float val;
  if (j < 128){
    val = s[n*128 + j];
  } else {
    int h = j - 128;
    float v0 = v[((size_t)n*128+h)*3+0], v1 = v[((size_t)n*128+h)*3+1], v2 = v[((size_t)n*128+h)*3+2];
    val = sqrtf(v0*v0 + v1*v1 + v2*v2 + 1e-12f);
  }
  int b = batch[n];
  atomicAdd(&addp[b*256 + j], val);
  if (j == 0) atomicAdd(&counts[b], 1.f);
}

__global__ void k_build_g(const float* __restrict__ addp, const float* __restrict__ counts,
                          const float* __restrict__ vn, float* __restrict__ gbuf){
  int i = blockIdx.x*256 + threadIdx.x;
  if (i >= G_*640) return;
  int g = i / 640, j = i % 640;
  float val;
  if (j < 256)       val = addp[g*256 + j];
  else if (j < 512)  val = addp[g*256 + (j-256)] / fmaxf(counts[g], 1.f);
  else               val = vn[g*128 + (j-512)];
  gbuf[i] = val;
}

// ---------------- host launcher ----------------

extern "C" void kernel_launch(void* const* d_in, const int* in_sizes, int n_in,
                              void* d_out, int out_size, void* d_ws, size_t ws_size,
                              hipStream_t stream)
{
  const float* x         = (const float*)d_in[0];
  const float* pos       = (const float*)d_in[1];
  const float* edist     = (const float*)d_in[2];
  const float* node_in_w = (const float*)d_in[3];
  const float* node_in_b = (const float*)d_in[4];
  const float* tm_w1 = (const float*)d_in[5];
  const float* tm_b1 = (const float*)d_in[6];
  const float* tm_w2 = (const float*)d_in[7];
  const float* tm_b2 = (const float*)d_in[8];
  const float* mm_w1 = (const float*)d_in[9];
  const float* mm_b1 = (const float*)d_in[10];
  const float* mm_w2 = (const float*)d_in[11];
  const float* mm_b2 = (const float*)d_in[12];
  const float* us_w1 = (const float*)d_in[13];
  const float* us_b1 = (const float*)d_in[14];
  const float* us_w2 = (const float*)d_in[15];
  const float* us_b2 = (const float*)d_in[16];
  const float* gv_w1 = (const float*)d_in[17];
  const float* gv_b1 = (const float*)d_in[18];
  const float* gv_w2 = (const float*)d_in[19];
  const float* gv_b2 = (const float*)d_in[20];
  const float* ln_g  = (const float*)d_in[21];
  const float* ln_b  = (const float*)d_in[22];
  const float* vn_init = (const float*)d_in[23];
  const float* v2n_w1 = (const float*)d_in[24];
  const float* v2n_b1 = (const float*)d_in[25];
  const float* v2n_w2 = (const float*)d_in[26];
  const float* v2n_b2 = (const float*)d_in[27];
  const float* n2v_w1 = (const float*)d_in[28];
  const float* n2v_b1 = (const float*)d_in[29];
  const float* n2v_w2 = (const float*)d_in[30];
  const float* n2v_b2 = (const float*)d_in[31];
  const float* head_w1 = (const float*)d_in[32];
  const float* head_b1 = (const float*)d_in[33];
  const float* head_w2 = (const float*)d_in[34];
  const float* head_b2 = (const float*)d_in[35];
  const int* ei    = (const int*)d_in[36];
  const int* t_kj  = (const int*)d_in[37];
  const int* t_ji  = (const int*)d_in[38];
  const int* batch = (const int*)d_in[39];
  float* out = (float*)d_out;

  // ---- workspace layout (~118.0 MiB) ----
  float* f = (float*)d_ws;
  size_t off = 0;
  auto alloc = [&](size_t n){ n = (n + 3) & ~(size_t)3; float* p = f + off; off += n; return p; };
  float*    vec    = alloc((size_t)E_*3);   // aliased: perm_t + perm_e after k_angle
  float*    dir    = alloc((size_t)E_*3);
  ushort_t* rbf16  = (ushort_t*)alloc((size_t)E_*16);
  float*    angle  = alloc((size_t)T_);
  float*    eagg   = alloc((size_t)E_*128);  // permuted-row layout; also hosts node scratch
  float*    s      = alloc((size_t)N_*128);
  ushort_t* s16    = (ushort_t*)alloc((size_t)N_*64);
  float*    v      = alloc((size_t)N_*384);
  float*    aggs   = alloc((size_t)N_*128);  // aliased: ihist in prologue
  float*    aggv   = alloc((size_t)N_*384);  // contiguous after aggs: zeroed together
  float*    rank_f = alloc((size_t)E_);      // rank_e (E ints)
  float*    wtbuf_f= alloc((size_t)376832);  // bf16 transposed weights (hi + node-lo)
  float*    vn     = alloc((size_t)G_*128);
  float*    tg2    = alloc((size_t)G_*128);
  float*    ssum   = alloc((size_t)G_*128);
  float*    addp   = alloc((size_t)G_*256);
  float*    counts = alloc((size_t)G_);
  float*    gbuf   = alloc((size_t)G_*640);

  if (off * sizeof(float) > ws_size){
    k_sentinel<<<1, 64, 0, stream>>>(out, G_);
    return;
  }

  // aliases
  int* perm_t = (int*)vec;
  int* perm_e = perm_t + T_;
  int* rank_e = (int*)rank_f;
  int* ihist  = (int*)aggs;           // prologue only
  int* isums  = ihist + 131072;
  // node-update scratch inside eagg (lifetime: after edge MLP, before next-layer eagg zero)
  ushort_t* a16h = (ushort_t*)eagg;                 // N*128 bf16
  ushort_t* a16l = a16h + (size_t)N_*128;
  ushort_t* vnh  = a16l + (size_t)N_*128;
  ushort_t* vnl  = vnh  + (size_t)N_*128;
  float*    s2   = (float*)(vnl + (size_t)N_*128);  // N*128 fp32

  ushort_t* wtp = (ushort_t*)wtbuf_f;
  ushort_t *wt_tm1[2], *wt_tm2[2], *wt_mm1[2], *wt_mm2[2];
  ushort_t *wt_us1h[2], *wt_us1l[2], *wt_us2h[2], *wt_us2l[2];
  ushort_t *wt_gv1h[2], *wt_gv1l[2], *wt_gv2h[2], *wt_gv2l[2];
  for (int l=0;l<2;l++){
    wt_tm1[l] = wtp; wtp += 128*96;
    wt_tm2[l] = wtp; wtp += 128*128;
    wt_mm1[l] = wtp; wtp += 128*416;
    wt_mm2[l] = wtp; wtp += 256*128;
    wt_us1h[l] = wtp; wtp += 128*384;
    wt_us1l[l] = wtp; wtp += 128*384;
    wt_us2h[l] = wtp; wtp += 128*128;
    wt_us2l[l] = wtp; wtp += 128*128;
    wt_gv1h[l] = wtp; wtp += 128*384;
    wt_gv1l[l] = wtp; wtp += 128*384;
    wt_gv2h[l] = wtp; wtp += 128*128;
    wt_gv2l[l] = wtp; wtp += 128*128;
  }

  auto zero = [&](float* p, long n){
    int blocks = (int)((n/4 + 255)/256); if (blocks > 16384) blocks = 16384; if (blocks < 1) blocks = 1;
    k_zero<<<blocks, 256, 0, stream>>>(p, n);
  };
  auto wt = [&](const float* W, ushort_t* Wt, int K, int C, int Kpad){
    int n = C*Kpad;
    k_wt<<<(n + 255)/256, 256, 0, stream>>>(W, Wt, K, C, Kpad);
  };
  auto wt2 = [&](const float* W, ushort_t* Whi, ushort_t* Wlo, int K, int C, int Kpad){
    int n = C*Kpad;
    k_wt2<<<(n + 255)/256, 256, 0, stream>>>(W, Whi, Wlo, K, C, Kpad);
  };
  auto csort = [&](const int* keys, const int* map, int M, int B, int* perm){
    zero((float*)ihist, B + (B+1023)/1024);
    if (map) k_hist2<<<(M+255)/256, 256, 0, stream>>>(keys, map, M, ihist);
    else     k_hist <<<(M+255)/256, 256, 0, stream>>>(keys, M, ihist);
    int nb = (B+1023)/1024;
    k_scan1<<<nb, 256, 0, stream>>>(ihist, ihist, isums, B);
    k_scan2<<<1, 64, 0, stream>>>(isums, nb);
    k_scan3<<<(B+255)/256, 256, 0, stream>>>(ihist, isums, B);
    if (map) k_fill2<<<(M+255)/256, 256, 0, stream>>>(keys, map, M, ihist, perm);
    else     k_fill <<<(M+255)/256, 256, 0, stream>>>(keys, M, ihist, perm);
  };

  // ---- prologue ----
  zero(v, (long)N_*384);
  k_init_vn<<<(G_*H_ + 255)/256, 256, 0, stream>>>(vn, vn_init);
  k_geom<<<(E_ + 255)/256, 256, 0, stream>>>(pos, edist, ei, vec, dir, rbf16);
  k_angle<<<(T_ + 255)/256, 256, 0, stream>>>(vec, t_kj, t_ji, angle);
  // edges sorted by dst, then rank_e = inverse perm, then triplets sorted by rank_e[ji]
  csort(ei+E_, nullptr, E_, N_, perm_e);
  k_invert<<<(E_+255)/256, 256, 0, stream>>>(perm_e, rank_e, E_);
  csort(t_ji, rank_e, T_, E_, perm_t);
  for (int l=0;l<2;l++){
    wt(tm_w1 + l*80*128,   wt_tm1[l],  80, 128,  96);
    wt(tm_w2 + l*128*128,  wt_tm2[l], 128, 128, 128);
    wt(mm_w1 + l*416*128,  wt_mm1[l], 416, 128, 416);
    wt(mm_w2 + l*128*256,  wt_mm2[l], 128, 256, 128);
    wt2(us_w1 + l*384*128, wt_us1h[l], wt_us1l[l], 384, 128, 384);
    wt2(us_w2 + l*128*128, wt_us2h[l], wt_us2l[l], 128, 128, 128);
    wt2(gv_w1 + l*384*128, wt_gv1h[l], wt_gv1l[l], 384, 128, 384);
    wt2(gv_w2 + l*128*128, wt_gv2h[l], wt_gv2l[l], 128, 128, 128);
  }
  k_gemm<<<512, 128, 0, stream>>>(x, node_in_w, node_in_b, s, N_, IND_);

  for (int l=0; l<L_; l++){
    // 1) s += v2n_mlp(vn)[batch]  (snapshots s16)
    k_small_mlp2<<<1, 256, 0, stream>>>(vn, v2n_w1, v2n_b1, v2n_w2, v2n_b2, tg2, 0);
    k_sadd_batch<<<(N_*H_ + 255)/256, 256, 0, stream>>>(s, tg2, batch, s16);

    // 2) triplet MLP (MFMA, 128-row blocks, barrier-free epilogue) -> eagg (permuted rows)
    zero(eagg, (long)E_*128);
    k_mlp2_mfma<<<T_/BROWS, 256, 0, stream>>>(1, perm_t, rank_e, t_kj, t_ji, rbf16, angle, s16, eagg,
        wt_tm1[l], tm_b1 + l*128, 96,
        wt_tm2[l], tm_b2 + l*128, 1, dir, eagg, nullptr);

    // 3) edge MLP (MFMA, 128-row blocks, barrier-free epilogue; eagg read sequentially)
    zero(aggs, (long)N_*512);
    k_mlp2_mfma<<<E_/BROWS, 256, 0, stream>>>(2, perm_e, nullptr, ei, ei + E_, rbf16, angle, s16, eagg,
        wt_mm1[l], mm_b1 + l*128, 416,
        wt_mm2[l], mm_b2 + l*256, 2, dir, aggs, aggv);

    // 4) prep ctx hi/lo pieces (into eagg space — eagg is dead until next layer)
    k_prep<<<(N_*H_ + 255)/256, 256, 0, stream>>>(aggs, v, a16h, a16l, vnh, vnl);

    // 5+6) node update (s2 = s + us_mlp) + gated v update; one wave/block, og split
    k_node_mfma<<<dim3(N_/32, 2), 64, 0, stream>>>(s, a16h, a16l, vnh, vnl, s2, v, aggv,
        wt_us1h[l], wt_us1l[l], us_b1 + l*128, wt_us2h[l], wt_us2l[l], us_b2 + l*128,
        wt_gv1h[l], wt_gv1l[l], gv_b1 + l*128, wt_gv2h[l], wt_gv2l[l], gv_b2 + l*128);

    // 7) s = silu(LN(s2))
    k_ln_silu<<<N_, 128, 0, stream>>>(s2, s, ln_g + l*128, ln_b + l*128);

    // 8) vn += n2v_mlp(segment_sum(s, batch))
    zero(ssum, (long)G_*128);
    k_segsum<<<(N_*H_ + 255)/256, 256, 0, stream>>>(s, batch, ssum);
    k_small_mlp2<<<1, 256, 0, stream>>>(ssum, n2v_w1, n2v_b1, n2v_w2, n2v_b2, vn, 1);
  }

  // ---- readout ----
  zero(addp, (long)(G_*256 + G_));   // addp and counts contiguous
  k_scatter_nf<<<(N_*256 + 255)/256, 256, 0, stream>>>(s, v, batch, addp, counts);
  k_build_g<<<(G_*640 + 255)/256, 256, 0, stream>>>(addp, counts, vn, gbuf);
  k_head<<<G_, 128, 0, stream>>>(gbuf, head_w1, head_b1, head_w2, head_b2, out);
}

// Round 11
// 1196.507 us; speedup vs baseline: 1.7935x; 1.0828x over previous
//
#include <hip/hip_runtime.h>
#include <math.h>

// ---- problem constants (from reference) ----
#define N_   8192
#define E_   131072
#define T_   262144
#define H_   128
#define IND_ 64
#define G_   32
#define L_   2

// generic fp32 GEMM tiling (node_in only)
#define CW 64
#define RB 16

// MFMA fused MLP tiling
#define MROWS 32     // rows per wave
#define BROWS 128    // rows per block (4 waves)
#define HSTRIDE 136  // LDS hidden row stride (bf16 elems)

// RBF constants
#define STEP_E  ((float)(5.0/31.0))
#define GAMMA_E ((float)(1.0/(2.0*((5.0/31.0)*(5.0/31.0) + 1e-12))))
#define PI_D    3.14159265358979323846
#define STEP_A  ((float)(PI_D/15.0))
#define GAMMA_A ((float)(1.0/(2.0*((PI_D/15.0)*(PI_D/15.0) + 1e-12))))

typedef __attribute__((ext_vector_type(8))) short short8;
typedef __attribute__((ext_vector_type(4))) float f32x4;
typedef unsigned short ushort_t;

static __device__ __forceinline__ float silu_f(float x){ return x / (1.f + expf(-x)); }
static __device__ __forceinline__ float sigmoid_f(float x){ return 1.f / (1.f + expf(-x)); }

static __device__ __forceinline__ ushort_t f2bf(float x){
  unsigned int u = __builtin_bit_cast(unsigned int, x);
  u += 0x7FFFu + ((u >> 16) & 1u);
  return (ushort_t)(u >> 16);
}
static __device__ __forceinline__ float bf2f(ushort_t h){
  unsigned int u = ((unsigned int)h) << 16;
  return __builtin_bit_cast(float, u);
}

// ---------------- small utility kernels ----------------

__global__ void k_zero(float* __restrict__ p, long n){
  long stride = (long)gridDim.x*256;
  long n4 = n >> 2;
  float4* p4 = (float4*)p;
  for (long i = (long)blockIdx.x*256 + threadIdx.x; i < n4; i += stride)
    p4[i] = make_float4(0.f,0.f,0.f,0.f);
  for (long i = (n4<<2) + (long)blockIdx.x*256 + threadIdx.x; i < n; i += stride)
    p[i] = 0.f;
}

__global__ void k_sentinel(float* __restrict__ p, int n){
  int i = blockIdx.x*256 + threadIdx.x;
  if (i < n) p[i] = 1.0e30f;
}

__global__ void k_init_vn(float* __restrict__ vn, const float* __restrict__ vn_init){
  int i = blockIdx.x*256 + threadIdx.x;
  if (i < G_*H_) vn[i] = vn_init[i & 127];
}

// weight convert+transpose (hi only): W fp32 [K][C] -> Wt bf16 [C][Kpad]
__global__ void k_wt(const float* __restrict__ W, ushort_t* __restrict__ Wt,
                     int K, int C, int Kpad){
  int i = blockIdx.x*256 + threadIdx.x;
  if (i >= C*Kpad) return;
  int c = i / Kpad, k = i % Kpad;
  Wt[i] = (k < K) ? f2bf(W[(size_t)k*C + c]) : (ushort_t)0;
}

// weight convert+transpose with residual: hi + lo (bf16x2 split)
__global__ void k_wt2(const float* __restrict__ W, ushort_t* __restrict__ Whi,
                      ushort_t* __restrict__ Wlo, int K, int C, int Kpad){
  int i = blockIdx.x*256 + threadIdx.x;
  if (i >= C*Kpad) return;
  int c = i / Kpad, k = i % Kpad;
  float w = (k < K) ? W[(size_t)k*C + c] : 0.f;
  ushort_t h = f2bf(w);
  Whi[i] = h;
  Wlo[i] = f2bf(w - bf2f(h));
}

// per-edge: vec, dir, edge RBF(32) in bf16
__global__ void k_geom(const float* __restrict__ pos, const float* __restrict__ dist,
                       const int* __restrict__ ei,
                       float* __restrict__ vec, float* __restrict__ dir,
                       ushort_t* __restrict__ rbf16){
  int e = blockIdx.x*256 + threadIdx.x;
  if (e >= E_) return;
  int s = ei[e], d = ei[E_ + e];
  float vx = pos[d*3+0] - pos[s*3+0];
  float vy = pos[d*3+1] - pos[s*3+1];
  float vz = pos[d*3+2] - pos[s*3+2];
  vec[e*3+0]=vx; vec[e*3+1]=vy; vec[e*3+2]=vz;
  float dd = dist[e];
  float inv = 1.f / (dd + 1e-9f);
  dir[e*3+0]=vx*inv; dir[e*3+1]=vy*inv; dir[e*3+2]=vz*inv;
  #pragma unroll
  for (int i=0;i<32;i++){
    float df = dd - i*STEP_E;
    rbf16[e*32+i] = f2bf(expf(-GAMMA_E*df*df));
  }
}

// per-triplet angle
__global__ void k_angle(const float* __restrict__ vec,
                        const int* __restrict__ kj, const int* __restrict__ ji,
                        float* __restrict__ angle){
  int t = blockIdx.x*256 + threadIdx.x;
  if (t >= T_) return;
  int ea = ji[t], eb = kj[t];
  float ax=vec[ea*3+0], ay=vec[ea*3+1], az=vec[ea*3+2];
  float bx=vec[eb*3+0], by=vec[eb*3+1], bz=vec[eb*3+2];
  float dot = ax*bx + ay*by + az*bz;
  float na = sqrtf(ax*ax+ay*ay+az*az + 1e-12f);
  float nb = sqrtf(bx*bx+by*by+bz*bz + 1e-12f);
  float c = dot / (na*nb + 1e-9f);
  c = fminf(fmaxf(c, -1.f + 1e-7f), 1.f - 1e-7f);
  angle[t] = acosf(c);
}

// ---------------- counting-sort kernels ----------------

__global__ void k_hist(const int* __restrict__ keys, int M, int* __restrict__ hist){
  int i = blockIdx.x*256 + threadIdx.x;
  if (i < M) atomicAdd(&hist[keys[i]], 1);
}

__global__ void k_hist2(const int* __restrict__ keys, const int* __restrict__ map,
                        int M, int* __restrict__ hist){
  int i = blockIdx.x*256 + threadIdx.x;
  if (i < M) atomicAdd(&hist[map[keys[i]]], 1);
}

__global__ void k_scan1(const int* __restrict__ in, int* __restrict__ out,
                        int* __restrict__ sums, int B){
  __shared__ int sh[1024];
  int base = blockIdx.x*1024, t = threadIdx.x;
  for (int j=t;j<1024;j+=256) sh[j] = (base+j<B) ? in[base+j] : 0;
  __syncthreads();
  for (int o=1;o<1024;o<<=1){
    int v[4];
    #pragma unroll
    for (int q=0;q<4;q++){ int idx=t+q*256; v[q]=(idx>=o)? sh[idx-o]:0; }
    __syncthreads();
    #pragma unroll
    for (int q=0;q<4;q++){ int idx=t+q*256; sh[idx]+=v[q]; }
    __syncthreads();
  }
  for (int j=t;j<1024;j+=256) if (base+j<B) out[base+j] = (j==0)?0:sh[j-1];
  if (t==0) sums[blockIdx.x] = sh[1023];
}

__global__ void k_scan2(int* __restrict__ sums, int nb){
  if (threadIdx.x==0 && blockIdx.x==0){
    int a=0;
    for (int i=0;i<nb;i++){ int x=sums[i]; sums[i]=a; a+=x; }
  }
}

__global__ void k_scan3(int* __restrict__ out, const int* __restrict__ sums, int B){
  int i = blockIdx.x*256+threadIdx.x;
  if (i<B) out[i] += sums[i>>10];
}

__global__ void k_fill(const int* __restrict__ keys, int M, int* __restrict__ cur,
                       int* __restrict__ perm){
  int i = blockIdx.x*256+threadIdx.x;
  if (i<M){ int p = atomicAdd(&cur[keys[i]],1); perm[p]=i; }
}

__global__ void k_fill2(const int* __restrict__ keys, const int* __restrict__ map,
                        int M, int* __restrict__ cur, int* __restrict__ perm){
  int i = blockIdx.x*256+threadIdx.x;
  if (i<M){ int p = atomicAdd(&cur[map[keys[i]]],1); perm[p]=i; }
}

__global__ void k_invert(const int* __restrict__ perm, int* __restrict__ rank, int M){
  int i = blockIdx.x*256+threadIdx.x;
  if (i<M) rank[perm[i]] = i;
}

// ---------------- MFMA fused 2-layer MLP + sorted segment-scatter ----------------
// Round-8 structure (verified best) with COMPILE-TIME SM/K1PAD/OUTGRP so the
// phase-A gather loop fully unrolls: branches fold, all gather loads issue
// early (many in flight) instead of one branchy iteration at a time.
// SM==1 (triplet): rows sorted by rank_e[ji]; scatter key = rank_e[ji]; eagg rows = rank.
// SM==2 (edge):    rows sorted by dst; eagg read positional (row = sorted position).
template<int SM, int K1PAD, int OUTGRP>
__launch_bounds__(256, 3)
__global__ void k_mlp2_mfma(
    const int* __restrict__ perm, const int* __restrict__ scatmap,
    const int* __restrict__ idx1, const int* __restrict__ idx2,
    const ushort_t* __restrict__ rbf16, const float* __restrict__ angle,
    const ushort_t* __restrict__ s16, const float* __restrict__ eagg_in,
    const ushort_t* __restrict__ W1t, const float* __restrict__ b1,
    const ushort_t* __restrict__ W2t, const float* __restrict__ b2,
    const float* __restrict__ dir,
    float* __restrict__ out0, float* __restrict__ out1)
{
  __shared__ ushort_t hid[BROWS*HSTRIDE];   // 34816 B
  __shared__ float mchunk[BROWS][33];       // 16896 B
  __shared__ int   segk[BROWS];
  __shared__ float dirs[BROWS][3];
  const int tid  = threadIdx.x;
  const int wave = tid >> 6;
  const int lane = tid & 63;
  const int n    = lane & 15;
  const int quad = lane >> 4;
  const int kq   = quad*8;
  const int wrow = blockIdx.x*BROWS + wave*MROWS;
  const int lrow = wave*MROWS;

  for (int i=tid; i<BROWS; i+=256){
    int e = perm[blockIdx.x*BROWS + i];
    int key = idx2[e];
    segk[i] = (SM == 1) ? scatmap[key] : key;
    if (SM == 2){
      dirs[i][0]=dir[e*3+0]; dirs[i][1]=dir[e*3+1]; dirs[i][2]=dir[e*3+2];
    }
  }

  const int e0 = perm[wrow + n];
  const int e1 = perm[wrow + 16 + n];

  int i1a = idx1[e0], i1b = idx1[e1];
  int i2a = idx2[e0], i2b = idx2[e1];
  float ang0 = 0.f, ang1 = 0.f;
  if (SM == 1){ ang0 = angle[e0]; ang1 = angle[e1]; }

  // ---------- phase A: hidden = silu(in @ W1 + b1) ----------
  f32x4 acc[2][8];
  #pragma unroll
  for (int rh=0;rh<2;rh++)
    #pragma unroll
    for (int ct=0;ct<8;ct++) acc[rh][ct] = (f32x4){0.f,0.f,0.f,0.f};

  #pragma unroll
  for (int k0 = 0; k0 < K1PAD; k0 += 32){
    short8 a0, a1;
    if (SM == 1){
      if (k0 == 0){
        a0 = *(const short8*)&rbf16[(size_t)i1a*32 + kq];
        a1 = *(const short8*)&rbf16[(size_t)i1b*32 + kq];
      } else if (k0 == 32){
        a0 = *(const short8*)&rbf16[(size_t)i2a*32 + kq];
        a1 = *(const short8*)&rbf16[(size_t)i2b*32 + kq];
      } else {
        #pragma unroll
        for (int j=0;j<8;j++){
          int kk = kq + j;
          float v0 = 0.f, v1 = 0.f;
          if (kk < 16){
            float c = (float)kk*STEP_A;
            float d0 = ang0 - c, d1 = ang1 - c;
            v0 = expf(-GAMMA_A*d0*d0); v1 = expf(-GAMMA_A*d1*d1);
          }
          a0[j] = (short)f2bf(v0); a1[j] = (short)f2bf(v1);
        }
      }
    } else {
      const int k = k0 + kq;
      if (k0 < 128){
        a0 = *(const short8*)&s16[(size_t)i1a*128 + k];
        a1 = *(const short8*)&s16[(size_t)i1b*128 + k];
      } else if (k0 < 256){
        a0 = *(const short8*)&s16[(size_t)i2a*128 + (k-128)];
        a1 = *(const short8*)&s16[(size_t)i2b*128 + (k-128)];
      } else if (k0 < 288){
        a0 = *(const short8*)&rbf16[(size_t)e0*32 + (k-256)];
        a1 = *(const short8*)&rbf16[(size_t)e1*32 + (k-256)];
      } else {
        // eagg stored in sorted-edge-position order -> sequential rows
        const float* p0 = &eagg_in[(size_t)(wrow + n)*128 + (k-288)];
        const float* p1 = &eagg_in[(size_t)(wrow + 16 + n)*128 + (k-288)];
        f32x4 x0 = *(const f32x4*)p0, x1 = *(const f32x4*)(p0+4);
        f32x4 y0 = *(const f32x4*)p1, y1 = *(const f32x4*)(p1+4);
        #pragma unroll
        for (int j=0;j<4;j++){
          a0[j] = (short)f2bf(x0[j]); a0[4+j] = (short)f2bf(x1[j]);
          a1[j] = (short)f2bf(y0[j]); a1[4+j] = (short)f2bf(y1[j]);
        }
      }
    }
    #pragma unroll
    for (int ct=0;ct<8;ct++){
      short8 b = *(const short8*)&W1t[(size_t)(ct*16 + n)*K1PAD + k0 + kq];
      acc[0][ct] = __builtin_amdgcn_mfma_f32_16x16x32_bf16(a0, b, acc[0][ct], 0,0,0);
      acc[1][ct] = __builtin_amdgcn_mfma_f32_16x16x32_bf16(a1, b, acc[1][ct], 0,0,0);
    }
  }

  // bias + silu -> LDS (wave-private rows; no barrier)
  #pragma unroll
  for (int rh=0;rh<2;rh++){
    #pragma unroll
    for (int ct=0;ct<8;ct++){
      int col = ct*16 + n;
      float bv = b1[col];
      #pragma unroll
      for (int reg=0;reg<4;reg++){
        int rloc = lrow + rh*16 + quad*4 + reg;
        float h = acc[rh][ct][reg] + bv;
        hid[rloc*HSTRIDE + col] = f2bf(silu_f(h));
      }
    }
  }

  // ---------- phase B: out = hidden @ W2 + b2, sorted segment-scatter ----------
  #pragma unroll
  for (int og=0; og<OUTGRP; og++){
    f32x4 acc2[2][8];
    #pragma unroll
    for (int rh=0;rh<2;rh++)
      #pragma unroll
      for (int ct=0;ct<8;ct++) acc2[rh][ct] = (f32x4){0.f,0.f,0.f,0.f};

    #pragma unroll
    for (int k0=0;k0<128;k0+=32){
      short8 a0 = *(const short8*)&hid[(size_t)(lrow + n)*HSTRIDE + k0 + kq];
      short8 a1 = *(const short8*)&hid[(size_t)(lrow + 16 + n)*HSTRIDE + k0 + kq];
      #pragma unroll
      for (int ct=0;ct<8;ct++){
        short8 b = *(const short8*)&W2t[(size_t)(og*128 + ct*16 + n)*128 + k0 + kq];
        acc2[0][ct] = __builtin_amdgcn_mfma_f32_16x16x32_bf16(a0, b, acc2[0][ct], 0,0,0);
        acc2[1][ct] = __builtin_amdgcn_mfma_f32_16x16x32_bf16(a1, b, acc2[1][ct], 0,0,0);
      }
    }

    for (int ch=0; ch<4; ch++){
      const int c0 = ch*32;
      __syncthreads();
      #pragma unroll
      for (int rh=0;rh<2;rh++){
        #pragma unroll
        for (int cti=0;cti<2;cti++){
          int ct = ch*2 + cti;
          int col = ct*16 + n;
          float bv = b2[og*128 + col];
          #pragma unroll
          for (int reg=0;reg<4;reg++){
            int r = lrow + rh*16 + quad*4 + reg;
            mchunk[r][col - c0] = acc2[rh][ct][reg] + bv;
          }
        }
      }
      __syncthreads();
      const int col = c0 + (tid & 31);
      const int w0r = (tid >> 5) * 16;
      if (SM == 1 || og == 0){
        float a = 0.f; int prev = segk[w0r];
        for (int j=0;j<16;j++){
          int r = w0r + j;
          int k = segk[r];
          if (k != prev){ atomicAdd(&out0[(size_t)prev*128 + col], a); a = 0.f; prev = k; }
          a += mchunk[r][col - c0];
        }
        atomicAdd(&out0[(size_t)prev*128 + col], a);
      } else {
        float ax=0.f, ay=0.f, az=0.f; int prev = segk[w0r];
        for (int j=0;j<16;j++){
          int r = w0r + j;
          int k = segk[r];
          if (k != prev){
            size_t b = ((size_t)prev*128 + col)*3;
            atomicAdd(&out1[b+0], ax); atomicAdd(&out1[b+1], ay); atomicAdd(&out1[b+2], az);
            ax=ay=az=0.f; prev = k;
          }
          float m = mchunk[r][col - c0];
          ax += m*dirs[r][0]; ay += m*dirs[r][1]; az += m*dirs[r][2];
        }
        size_t b = ((size_t)prev*128 + col)*3;
        atomicAdd(&out1[b+0], ax); atomicAdd(&out1[b+1], ay); atomicAdd(&out1[b+2], az);
      }
    }
  }
}

// ---------------- prep: split aggs and ||v|| into bf16 hi/lo ----------------
__global__ void k_prep(const float* __restrict__ aggs, const float* __restrict__ v,
                       ushort_t* __restrict__ a16h, ushort_t* __restrict__ a16l,
                       ushort_t* __restrict__ vnh,  ushort_t* __restrict__ vnl){
  int i = blockIdx.x*256 + threadIdx.x;
  if (i >= N_*H_) return;
  float a = aggs[i];
  ushort_t ah = f2bf(a);
  a16h[i] = ah; a16l[i] = f2bf(a - bf2f(ah));
  float v0 = v[(size_t)i*3+0], v1 = v[(size_t)i*3+1], v2 = v[(size_t)i*3+2];
  float nv = sqrtf(v0*v0 + v1*v1 + v2*v2 + 1e-12f);
  ushort_t nh = f2bf(nv);
  vnh[i] = nh; vnl[i] = f2bf(nv - bf2f(nh));
}

// ---------------- MFMA node-update kernel (one wave per block, og = blockIdx.y) ----------------
__launch_bounds__(64, 4)
__global__ void k_node_mfma(
    const float* __restrict__ s_in,
    const ushort_t* __restrict__ a16h, const ushort_t* __restrict__ a16l,
    const ushort_t* __restrict__ vnh,  const ushort_t* __restrict__ vnl,
    float* __restrict__ s2, float* __restrict__ v_out,
    const float* __restrict__ aggv,
    const ushort_t* __restrict__ us1h, const ushort_t* __restrict__ us1l, const float* __restrict__ us_b1,
    const ushort_t* __restrict__ us2h, const ushort_t* __restrict__ us2l, const float* __restrict__ us_b2,
    const ushort_t* __restrict__ gv1h, const ushort_t* __restrict__ gv1l, const float* __restrict__ gv_b1,
    const ushort_t* __restrict__ gv2h, const ushort_t* __restrict__ gv2l, const float* __restrict__ gv_b2)
{
  __shared__ ushort_t hidh[32*HSTRIDE];   // 8704 B
  __shared__ ushort_t hidl[32*HSTRIDE];   // 8704 B
  const int lane = threadIdx.x;
  const int n    = lane & 15;
  const int quad = lane >> 4;
  const int kq   = quad*8;
  const int og   = blockIdx.y;
  const int wrow = blockIdx.x*32;
  const int r0 = wrow + n;
  const int r1 = wrow + 16 + n;

  const ushort_t* W1h = og ? gv1h : us1h;
  const ushort_t* W1l = og ? gv1l : us1l;
  const float*    B1  = og ? gv_b1 : us_b1;
  const ushort_t* W2h = og ? gv2h : us2h;
  const ushort_t* W2l = og ? gv2l : us2l;
  const float*    B2  = og ? gv_b2 : us_b2;

  // ---------- phase A: hidden = silu(ctx @ W1 + b1), bf16x3 ----------
  f32x4 acc[2][8];
  #pragma unroll
  for (int rh=0;rh<2;rh++)
    #pragma unroll
    for (int ct=0;ct<8;ct++) acc[rh][ct] = (f32x4){0.f,0.f,0.f,0.f};

  #pragma unroll
  for (int k0=0; k0<384; k0+=32){
    short8 ah0, al0, ah1, al1;
    const int k = k0 + kq;
    if (k0 < 128){
      const float* p0 = &s_in[(size_t)r0*128 + k];
      const float* p1 = &s_in[(size_t)r1*128 + k];
      f32x4 x0 = *(const f32x4*)p0, x1 = *(const f32x4*)(p0+4);
      f32x4 y0 = *(const f32x4*)p1, y1 = *(const f32x4*)(p1+4);
      #pragma unroll
      for (int j=0;j<4;j++){
        ushort_t h;
        h = f2bf(x0[j]); ah0[j]   = (short)h; al0[j]   = (short)f2bf(x0[j] - bf2f(h));
        h = f2bf(x1[j]); ah0[4+j] = (short)h; al0[4+j] = (short)f2bf(x1[j] - bf2f(h));
        h = f2bf(y0[j]); ah1[j]   = (short)h; al1[j]   = (short)f2bf(y0[j] - bf2f(h));
        h = f2bf(y1[j]); ah1[4+j] = (short)h; al1[4+j] = (short)f2bf(y1[j] - bf2f(h));
      }
    } else if (k0 < 256){
      int kk = k - 128;
      ah0 = *(const short8*)&a16h[(size_t)r0*128 + kk];
      al0 = *(const short8*)&a16l[(size_t)r0*128 + kk];
      ah1 = *(const short8*)&a16h[(size_t)r1*128 + kk];
      al1 = *(const short8*)&a16l[(size_t)r1*128 + kk];
    } else {
      int kk = k - 256;
      ah0 = *(const short8*)&vnh[(size_t)r0*128 + kk];
      al0 = *(const short8*)&vnl[(size_t)r0*128 + kk];
      ah1 = *(const short8*)&vnh[(size_t)r1*128 + kk];
      al1 = *(const short8*)&vnl[(size_t)r1*128 + kk];
    }
    #pragma unroll
    for (int ct=0;ct<8;ct++){
      short8 bh = *(const short8*)&W1h[(size_t)(ct*16 + n)*384 + k0 + kq];
      short8 bl = *(const short8*)&W1l[(size_t)(ct*16 + n)*384 + k0 + kq];
      acc[0][ct] = __builtin_amdgcn_mfma_f32_16x16x32_bf16(ah0, bh, acc[0][ct], 0,0,0);
      acc[0][ct] = __builtin_amdgcn_mfma_f32_16x16x32_bf16(al0, bh, acc[0][ct], 0,0,0);
      acc[0][ct] = __builtin_amdgcn_mfma_f32_16x16x32_bf16(ah0, bl, acc[0][ct], 0,0,0);
      acc[1][ct] = __builtin_amdgcn_mfma_f32_16x16x32_bf16(ah1, bh, acc[1][ct], 0,0,0);
      acc[1][ct] = __builtin_amdgcn_mfma_f32_16x16x32_bf16(al1, bh, acc[1][ct], 0,0,0);
      acc[1][ct] = __builtin_amdgcn_mfma_f32_16x16x32_bf16(ah1, bl, acc[1][ct], 0,0,0);
    }
  }

  #pragma unroll
  for (int rh=0;rh<2;rh++){
    #pragma unroll
    for (int ct=0;ct<8;ct++){
      int col = ct*16 + n;
      float bv = B1[col];
      #pragma unroll
      for (int reg=0;reg<4;reg++){
        int rloc = rh*16 + quad*4 + reg;
        float h = silu_f(acc[rh][ct][reg] + bv);
        ushort_t hh = f2bf(h);
        hidh[rloc*HSTRIDE + col] = hh;
        hidl[rloc*HSTRIDE + col] = f2bf(h - bf2f(hh));
      }
    }
  }

  // ---------- phase B ----------
  f32x4 acc2[2][8];
  #pragma unroll
  for (int rh=0;rh<2;rh++)
    #pragma unroll
    for (int ct=0;ct<8;ct++) acc2[rh][ct] = (f32x4){0.f,0.f,0.f,0.f};

  #pragma unroll
  for (int k0=0;k0<128;k0+=32){
    short8 ah0 = *(const short8*)&hidh[(size_t)(n)*HSTRIDE + k0 + kq];
    short8 ah1 = *(const short8*)&hidh[(size_t)(16 + n)*HSTRIDE + k0 + kq];
    short8 al0 = *(const short8*)&hidl[(size_t)(n)*HSTRIDE + k0 + kq];
    short8 al1 = *(const short8*)&hidl[(size_t)(16 + n)*HSTRIDE + k0 + kq];
    #pragma unroll
    for (int ct=0;ct<8;ct++){
      short8 bh = *(const short8*)&W2h[(size_t)(ct*16 + n)*128 + k0 + kq];
      short8 bl = *(const short8*)&W2l[(size_t)(ct*16 + n)*128 + k0 + kq];
      acc2[0][ct] = __builtin_amdgcn_mfma_f32_16x16x32_bf16(ah0, bh, acc2[0][ct], 0,0,0);
      acc2[0][ct] = __builtin_amdgcn_mfma_f32_16x16x32_bf16(al0, bh, acc2[0][ct], 0,0,0);
      acc2[0][ct] = __builtin_amdgcn_mfma_f32_16x16x32_bf16(ah0, bl, acc2[0][ct], 0,0,0);
      acc2[1][ct] = __builtin_amdgcn_mfma_f32_16x16x32_bf16(ah1, bh, acc2[1][ct], 0,0,0);
      acc2[1][ct] = __builtin_amdgcn_mfma_f32_16x16x32_bf16(al1, bh, acc2[1][ct], 0,0,0);
      acc2[1][ct] = __builtin_amdgcn_mfma_f32_16x16x32_bf16(ah1, bl, acc2[1][ct], 0,0,0);
    }
  }

  if (og == 0){
    #pragma unroll
    for (int rh=0;rh<2;rh++){
      #pragma unroll
      for (int ct=0;ct<8;ct++){
        int col = ct*16 + n;
        float bv = B2[col];
        #pragma unroll
        for (int reg=0;reg<4;reg++){
          int row = wrow + rh*16 + quad*4 + reg;
          size_t idx = (size_t)row*128 + col;
          s2[idx] = s_in[idx] + acc2[rh][ct][reg] + bv;
        }
      }
    }
  } else {
    #pragma unroll
    for (int rh=0;rh<2;rh++){
      #pragma unroll
      for (int ct=0;ct<8;ct++){
        int col = ct*16 + n;
        float bv = B2[col];
        #pragma unroll
        for (int reg=0;reg<4;reg++){
          int row = wrow + rh*16 + quad*4 + reg;
          size_t idx = (size_t)row*128 + col;
          float g = sigmoid_f(acc2[rh][ct][reg] + bv);
          size_t base = idx*3;
          v_out[base+0] += g*aggv[base+0];
          v_out[base+1] += g*aggv[base+1];
          v_out[base+2] += g*aggv[base+2];
        }
      }
    }
  }
}

// ---------------- generic fp32 row-MLP GEMM (node_in only) ----------------
__launch_bounds__(128)
__global__ void k_gemm(const float* __restrict__ A,
                       const float* __restrict__ W,
                       const float* __restrict__ bias,
                       float* __restrict__ C, int R, int K)
{
  __shared__ float ws[CW*128];
  __shared__ float as[RB][CW];
  const int tid = threadIdx.x;
  const int nchunk = (K + CW - 1) / CW;

  for (int rb = blockIdx.x*RB; rb < R; rb += gridDim.x*RB){
    float acc[RB];
    #pragma unroll
    for (int r=0;r<RB;r++) acc[r] = 0.f;

    for (int c=0;c<nchunk;c++){
      const int k0 = c*CW;
      for (int i=tid; i<CW*128; i+=128){
        int kk = i >> 7, col = i & 127;
        int k = k0 + kk;
        ws[i] = (k < K) ? W[k*128 + col] : 0.f;
      }
      for (int i=tid; i<RB*CW; i+=128){
        int r  = i >> 6, kk = i & 63;
        int k  = k0 + kk;
        as[r][kk] = (k < K) ? A[(long)(rb+r)*K + k] : 0.f;
      }
      __syncthreads();
      #pragma unroll 4
      for (int kq2=0; kq2<CW/4; kq2++){
        float w0 = ws[(4*kq2+0)*128 + tid];
        float w1 = ws[(4*kq2+1)*128 + tid];
        float w2 = ws[(4*kq2+2)*128 + tid];
        float w3 = ws[(4*kq2+3)*128 + tid];
        #pragma unroll
        for (int r=0;r<RB;r++){
          const float4 av = *reinterpret_cast<const float4*>(&as[r][4*kq2]);
          acc[r] = fmaf(av.x, w0, acc[r]);
          acc[r] = fmaf(av.y, w1, acc[r]);
          acc[r] = fmaf(av.z, w2, acc[r]);
          acc[r] = fmaf(av.w, w3, acc[r]);
        }
      }
      __syncthreads();
    }

    const float bv = bias[tid];
    #pragma unroll
    for (int r=0;r<RB;r++)
      C[(long)(rb+r)*128 + tid] = acc[r] + bv;
  }
}

// ---------------- small fused kernels ----------------

__launch_bounds__(256)
__global__ void k_small_mlp2(const float* __restrict__ in,
                             const float* __restrict__ w1, const float* __restrict__ b1,
                             const float* __restrict__ w2, const float* __restrict__ b2,
                             float* __restrict__ outp, int accumulate){
  __shared__ float a[32][128];
  __shared__ float h[32][128];
  int tid = threadIdx.x;
  for (int i=tid;i<32*128;i+=256) a[i>>7][i&127] = in[i];
  __syncthreads();
  int col = tid & 127, rg = tid >> 7;
  float acc[16];
  #pragma unroll
  for (int r=0;r<16;r++) acc[r]=0.f;
  for (int k=0;k<128;k++){
    float w = w1[k*128+col];
    #pragma unroll
    for (int r=0;r<16;r++) acc[r] = fmaf(a[rg*16+r][k], w, acc[r]);
  }
  {
    float bv = b1[col];
    #pragma unroll
    for (int r=0;r<16;r++) h[rg*16+r][col] = silu_f(acc[r]+bv);
  }
  __syncthreads();
  #pragma unroll
  for (int r=0;r<16;r++) acc[r]=0.f;
  for (int k=0;k<128;k++){
    float w = w2[k*128+col];
    #pragma unroll
    for (int r=0;r<16;r++) acc[r] = fmaf(h[rg*16+r][k], w, acc[r]);
  }
  {
    float bv = b2[col];
    #pragma unroll
    for (int r=0;r<16;r++){
      int idx = (rg*16+r)*128+col;
      float val = acc[r]+bv;
      outp[idx] = accumulate ? outp[idx]+val : val;
    }
  }
}

__global__ void k_head(const float* __restrict__ gbuf,
                       const float* __restrict__ w1, const float* __restrict__ b1,
                       const float* __restrict__ w2, const float* __restrict__ b2,
                       float* __restrict__ outp){
  __shared__ float red[128];
  int g = blockIdx.x, tid = threadIdx.x;
  float acc = 0.f;
  for (int k=0;k<640;k++) acc = fmaf(gbuf[g*640+k], w1[k*128+tid], acc);
  float h = silu_f(acc + b1[tid]);
  red[tid] = h * w2[tid];
  __syncthreads();
  for (int o=64;o>0;o>>=1){ if (tid<o) red[tid]+=red[tid+o]; __syncthreads(); }
  if (tid == 0) outp[g] = red[0] + b2[0];
}

// ---------------- elementwise / reduction kernels ----------------

__global__ void k_sadd_batch(float* __restrict__ s, const float* __restrict__ t2,
                             const int* __restrict__ batch, ushort_t* __restrict__ s16){
  int i = blockIdx.x*256 + threadIdx.x;
  if (i >= N_*H_) return;
  int n = i >> 7, h = i & 127;
  float v = s[i] + t2[batch[n]*128 + h];
  s[i] = v;
  s16[i] = f2bf(v);
}

__global__ void k_ln_silu(const float* __restrict__ in, float* __restrict__ outp,
                          const float* __restrict__ g, const float* __restrict__ b){
  __shared__ float red[128];
  int n = blockIdx.x, tid = threadIdx.x;
  float x = in[n*128 + tid];
  red[tid] = x; __syncthreads();
  for (int o=64;o>0;o>>=1){ if (tid<o) red[tid]+=red[tid+o]; __syncthreads(); }
  float mu = red[0] * (1.f/128.f);
  __syncthreads();
  float dx = x - mu;
  red[tid] = dx*dx; __syncthreads();
  for (int o=64;o>0;o>>=1){ if (tid<o) red[tid]+=red[tid+o]; __syncthreads(); }
  float var = red[0] * (1.f/128.f);
  float y = dx * rsqrtf(var + 1e-5f) * g[tid] + b[tid];
  outp[n*128 + tid] = silu_f(y);
}

__global__ void k_segsum(const float* __restrict__ s, const int* __restrict__ batch,
                         float* __restrict__ ssum){
  int i = blockIdx.x*256 + threadIdx.x;
  if (i >= N_*H_) return;
  int n = i >> 7, h = i & 127;
  atomicAdd(&ssum[batch[n]*128 + h], s[i]);
}

__global__ void k_scatter_nf(const float* __restrict__ s, const float* __restrict__ v,
                             const int* __restrict__ batch, float* __restrict__ addp,
                             float* __restrict__ counts){
  int i = blockIdx.x*256 + threadIdx.x;
  if (i >= N_*256) return;
  int n = i >> 8, j = i & 255;
  float val;
  if (j < 128){
    val = s[n*128 + j];
  } else {
    int h = j - 128;
    float v0 = v[((size_t)n*128+h)*3+0], v1 = v[((size_t)n*128+h)*3+1], v2 = v[((size_t)n*128+h)*3+2];
    val = sqrtf(v0*v0 + v1*v1 + v2*v2 + 1e-12f);
  }
  int b = batch[n];
  atomicAdd(&addp[b*256 + j], val);
  if (j == 0) atomicAdd(&counts[b], 1.f);
}

__global__ void k_build_g(const float* __restrict__ addp, const float* __restrict__ counts,
                          const float* __restrict__ vn, float* __restrict__ gbuf){
  int i = blockIdx.x*256 + threadIdx.x;
  if (i >= G_*640) return;
  int g = i / 640, j = i % 640;
  float val;
  if (j < 256)       val = addp[g*256 + j];
  else if (j < 512)  val = addp[g*256 + (j-256)] / fmaxf(counts[g], 1.f);
  else               val = vn[g*128 + (j-512)];
  gbuf[i] = val;
}

// ---------------- host launcher ----------------

extern "C" void kernel_launch(void* const* d_in, const int* in_sizes, int n_in,
                              void* d_out, int out_size, void* d_ws, size_t ws_size,
                              hipStream_t stream)
{
  const float* x         = (const float*)d_in[0];
  const float* pos       = (const float*)d_in[1];
  const float* edist     = (const float*)d_in[2];
  const float* node_in_w = (const float*)d_in[3];
  const float* node_in_b = (const float*)d_in[4];
  const float* tm_w1 = (const float*)d_in[5];
  const float* tm_b1 = (const float*)d_in[6];
  const float* tm_w2 = (const float*)d_in[7];
  const float* tm_b2 = (const float*)d_in[8];
  const float* mm_w1 = (const float*)d_in[9];
  const float* mm_b1 = (const float*)d_in[10];
  const float* mm_w2 = (const float*)d_in[11];
  const float* mm_b2 = (const float*)d_in[12];
  const float* us_w1 = (const float*)d_in[13];
  const float* us_b1 = (const float*)d_in[14];
  const float* us_w2 = (const float*)d_in[15];
  const float* us_b2 = (const float*)d_in[16];
  const float* gv_w1 = (const float*)d_in[17];
  const float* gv_b1 = (const float*)d_in[18];
  const float* gv_w2 = (const float*)d_in[19];
  const float* gv_b2 = (const float*)d_in[20];
  const float* ln_g  = (const float*)d_in[21];
  const float* ln_b  = (const float*)d_in[22];
  const float* vn_init = (const float*)d_in[23];
  const float* v2n_w1 = (const float*)d_in[24];
  const float* v2n_b1 = (const float*)d_in[25];
  const float* v2n_w2 = (const float*)d_in[26];
  const float* v2n_b2 = (const float*)d_in[27];
  const float* n2v_w1 = (const float*)d_in[28];
  const float* n2v_b1 = (const float*)d_in[29];
  const float* n2v_w2 = (const float*)d_in[30];
  const float* n2v_b2 = (const float*)d_in[31];
  const float* head_w1 = (const float*)d_in[32];
  const float* head_b1 = (const float*)d_in[33];
  const float* head_w2 = (const float*)d_in[34];
  const float* head_b2 = (const float*)d_in[35];
  const int* ei    = (const int*)d_in[36];
  const int* t_kj  = (const int*)d_in[37];
  const int* t_ji  = (const int*)d_in[38];
  const int* batch = (const int*)d_in[39];
  float* out = (float*)d_out;

  // ---- workspace layout (~118.0 MiB) ----
  float* f = (float*)d_ws;
  size_t off = 0;
  auto alloc = [&](size_t n){ n = (n + 3) & ~(size_t)3; float* p = f + off; off += n; return p; };
  float*    vec    = alloc((size_t)E_*3);   // aliased: perm_t + perm_e after k_angle
  float*    dir    = alloc((size_t)E_*3);
  ushort_t* rbf16  = (ushort_t*)alloc((size_t)E_*16);
  float*    angle  = alloc((size_t)T_);
  float*    eagg   = alloc((size_t)E_*128);  // permuted-row layout; also hosts node scratch
  float*    s      = alloc((size_t)N_*128);
  ushort_t* s16    = (ushort_t*)alloc((size_t)N_*64);
  float*    v      = alloc((size_t)N_*384);
  float*    aggs   = alloc((size_t)N_*128);  // aliased: ihist in prologue
  float*    aggv   = alloc((size_t)N_*384);  // contiguous after aggs: zeroed together
  float*    rank_f = alloc((size_t)E_);      // rank_e (E ints)
  float*    wtbuf_f= alloc((size_t)376832);  // bf16 transposed weights (hi + node-lo)
  float*    vn     = alloc((size_t)G_*128);
  float*    tg2    = alloc((size_t)G_*128);
  float*    ssum   = alloc((size_t)G_*128);
  float*    addp   = alloc((size_t)G_*256);
  float*    counts = alloc((size_t)G_);
  float*    gbuf   = alloc((size_t)G_*640);

  if (off * sizeof(float) > ws_size){
    k_sentinel<<<1, 64, 0, stream>>>(out, G_);
    return;
  }

  // aliases
  int* perm_t = (int*)vec;
  int* perm_e = perm_t + T_;
  int* rank_e = (int*)rank_f;
  int* ihist  = (int*)aggs;           // prologue only
  int* isums  = ihist + 131072;
  // node-update scratch inside eagg (lifetime: after edge MLP, before next-layer eagg zero)
  ushort_t* a16h = (ushort_t*)eagg;                 // N*128 bf16
  ushort_t* a16l = a16h + (size_t)N_*128;
  ushort_t* vnh  = a16l + (size_t)N_*128;
  ushort_t* vnl  = vnh  + (size_t)N_*128;
  float*    s2   = (float*)(vnl + (size_t)N_*128);  // N*128 fp32

  ushort_t* wtp = (ushort_t*)wtbuf_f;
  ushort_t *wt_tm1[2], *wt_tm2[2], *wt_mm1[2], *wt_mm2[2];
  ushort_t *wt_us1h[2], *wt_us1l[2], *wt_us2h[2], *wt_us2l[2];
  ushort_t *wt_gv1h[2], *wt_gv1l[2], *wt_gv2h[2], *wt_gv2l[2];
  for (int l=0;l<2;l++){
    wt_tm1[l] = wtp; wtp += 128*96;
    wt_tm2[l] = wtp; wtp += 128*128;
    wt_mm1[l] = wtp; wtp += 128*416;
    wt_mm2[l] = wtp; wtp += 256*128;
    wt_us1h[l] = wtp; wtp += 128*384;
    wt_us1l[l] = wtp; wtp += 128*384;
    wt_us2h[l] = wtp; wtp += 128*128;
    wt_us2l[l] = wtp; wtp += 128*128;
    wt_gv1h[l] = wtp; wtp += 128*384;
    wt_gv1l[l] = wtp; wtp += 128*384;
    wt_gv2h[l] = wtp; wtp += 128*128;
    wt_gv2l[l] = wtp; wtp += 128*128;
  }

  auto zero = [&](float* p, long n){
    int blocks = (int)((n/4 + 255)/256); if (blocks > 16384) blocks = 16384; if (blocks < 1) blocks = 1;
    k_zero<<<blocks, 256, 0, stream>>>(p, n);
  };
  auto wt = [&](const float* W, ushort_t* Wt, int K, int C, int Kpad){
    int n = C*Kpad;
    k_wt<<<(n + 255)/256, 256, 0, stream>>>(W, Wt, K, C, Kpad);
  };
  auto wt2 = [&](const float* W, ushort_t* Whi, ushort_t* Wlo, int K, int C, int Kpad){
    int n = C*Kpad;
    k_wt2<<<(n + 255)/256, 256, 0, stream>>>(W, Whi, Wlo, K, C, Kpad);
  };
  auto csort = [&](const int* keys, const int* map, int M, int B, int* perm){
    zero((float*)ihist, B + (B+1023)/1024);
    if (map) k_hist2<<<(M+255)/256, 256, 0, stream>>>(keys, map, M, ihist);
    else     k_hist <<<(M+255)/256, 256, 0, stream>>>(keys, M, ihist);
    int nb = (B+1023)/1024;
    k_scan1<<<nb, 256, 0, stream>>>(ihist, ihist, isums, B);
    k_scan2<<<1, 64, 0, stream>>>(isums, nb);
    k_scan3<<<(B+255)/256, 256, 0, stream>>>(ihist, isums, B);
    if (map) k_fill2<<<(M+255)/256, 256, 0, stream>>>(keys, map, M, ihist, perm);
    else     k_fill <<<(M+255)/256, 256, 0, stream>>>(keys, M, ihist, perm);
  };

  // ---- prologue ----
  zero(v, (long)N_*384);
  k_init_vn<<<(G_*H_ + 255)/256, 256, 0, stream>>>(vn, vn_init);
  k_geom<<<(E_ + 255)/256, 256, 0, stream>>>(pos, edist, ei, vec, dir, rbf16);
  k_angle<<<(T_ + 255)/256, 256, 0, stream>>>(vec, t_kj, t_ji, angle);
  // edges sorted by dst, then rank_e = inverse perm, then triplets sorted by rank_e[ji]
  csort(ei+E_, nullptr, E_, N_, perm_e);
  k_invert<<<(E_+255)/256, 256, 0, stream>>>(perm_e, rank_e, E_);
  csort(t_ji, rank_e, T_, E_, perm_t);
  for (int l=0;l<2;l++){
    wt(tm_w1 + l*80*128,   wt_tm1[l],  80, 128,  96);
    wt(tm_w2 + l*128*128,  wt_tm2[l], 128, 128, 128);
    wt(mm_w1 + l*416*128,  wt_mm1[l], 416, 128, 416);
    wt(mm_w2 + l*128*256,  wt_mm2[l], 128, 256, 128);
    wt2(us_w1 + l*384*128, wt_us1h[l], wt_us1l[l], 384, 128, 384);
    wt2(us_w2 + l*128*128, wt_us2h[l], wt_us2l[l], 128, 128, 128);
    wt2(gv_w1 + l*384*128, wt_gv1h[l], wt_gv1l[l], 384, 128, 384);
    wt2(gv_w2 + l*128*128, wt_gv2h[l], wt_gv2l[l], 128, 128, 128);
  }
  k_gemm<<<512, 128, 0, stream>>>(x, node_in_w, node_in_b, s, N_, IND_);

  for (int l=0; l<L_; l++){
    // 1) s += v2n_mlp(vn)[batch]  (snapshots s16)
    k_small_mlp2<<<1, 256, 0, stream>>>(vn, v2n_w1, v2n_b1, v2n_w2, v2n_b2, tg2, 0);
    k_sadd_batch<<<(N_*H_ + 255)/256, 256, 0, stream>>>(s, tg2, batch, s16);

    // 2) triplet MLP (MFMA, compile-time unrolled gather loop) -> eagg (permuted rows)
    zero(eagg, (long)E_*128);
    k_mlp2_mfma<1,96,1><<<T_/BROWS, 256, 0, stream>>>(perm_t, rank_e, t_kj, t_ji,
        rbf16, angle, s16, eagg,
        wt_tm1[l], tm_b1 + l*128, wt_tm2[l], tm_b2 + l*128, dir, eagg, nullptr);

    // 3) edge MLP (MFMA, compile-time unrolled gather loop; eagg read sequentially)
    zero(aggs, (long)N_*512);
    k_mlp2_mfma<2,416,2><<<E_/BROWS, 256, 0, stream>>>(perm_e, nullptr, ei, ei + E_,
        rbf16, angle, s16, eagg,
        wt_mm1[l], mm_b1 + l*128, wt_mm2[l], mm_b2 + l*256, dir, aggs, aggv);

    // 4) prep ctx hi/lo pieces (into eagg space — eagg is dead until next layer)
    k_prep<<<(N_*H_ + 255)/256, 256, 0, stream>>>(aggs, v, a16h, a16l, vnh, vnl);

    // 5+6) node update (s2 = s + us_mlp) + gated v update; one wave/block, og split
    k_node_mfma<<<dim3(N_/32, 2), 64, 0, stream>>>(s, a16h, a16l, vnh, vnl, s2, v, aggv,
        wt_us1h[l], wt_us1l[l], us_b1 + l*128, wt_us2h[l], wt_us2l[l], us_b2 + l*128,
        wt_gv1h[l], wt_gv1l[l], gv_b1 + l*128, wt_gv2h[l], wt_gv2l[l], gv_b2 + l*128);

    // 7) s = silu(LN(s2))
    k_ln_silu<<<N_, 128, 0, stream>>>(s2, s, ln_g + l*128, ln_b + l*128);

    // 8) vn += n2v_mlp(segment_sum(s, batch))
    zero(ssum, (long)G_*128);
    k_segsum<<<(N_*H_ + 255)/256, 256, 0, stream>>>(s, batch, ssum);
    k_small_mlp2<<<1, 256, 0, stream>>>(ssum, n2v_w1, n2v_b1, n2v_w2, n2v_b2, vn, 1);
  }

  // ---- readout ----
  zero(addp, (long)(G_*256 + G_));   // addp and counts contiguous
  k_scatter_nf<<<(N_*256 + 255)/256, 256, 0, stream>>>(s, v, batch, addp, counts);
  k_build_g<<<(G_*640 + 255)/256, 256, 0, stream>>>(addp, counts, vn, gbuf);
  k_head<<<G_, 128, 0, stream>>>(gbuf, head_w1, head_b1, head_w2, head_b2, out);
}